// Round 1
// baseline (2047.290 us; speedup 1.0000x reference)
//
#include <hip/hip_runtime.h>
#include <hip/hip_bf16.h>
#include <math.h>

// Model: B=64,S=100,D=768,H=8,P=8,FF=3072,HD=96, 4 shared layers.
// Strategy:
//  - param path (pooled -> proj -> LN -> param_bias) computed ONCE (layer-shared).
//  - big GEMMs in bf16 MFMA (16x16x32), 128x128 tile, fp32 accumulate.
//  - LN / softmax / attention / classifier in fp32.

typedef __attribute__((ext_vector_type(8))) short bf16x8;
typedef __attribute__((ext_vector_type(4))) float f32x4;

#define BB 64
#define SS 100
#define DD 768
#define HH 8
#define HD 96
#define FF_ 3072
#define ROWS 6400           // B*S
#define LN10000 9.210340371976184f

// ---------------- block-wide sum over 256 threads ----------------
__device__ __forceinline__ float block_sum256(float v, float* sbuf) {
#pragma unroll
  for (int o = 32; o > 0; o >>= 1) v += __shfl_xor(v, o, 64);
  int tid = threadIdx.x;
  __syncthreads();
  if ((tid & 63) == 0) sbuf[tid >> 6] = v;
  __syncthreads();
  return sbuf[0] + sbuf[1] + sbuf[2] + sbuf[3];
}

// ---------------- fp32 [K,N] -> bf16 [N,K] transpose-convert ----------------
__global__ void convert_transpose(const float* __restrict__ in,
                                  __hip_bfloat16* __restrict__ out,
                                  int K, int N) {
  __shared__ float t[32][33];
  int n0 = blockIdx.x * 32, k0 = blockIdx.y * 32;
  int tid = threadIdx.x;
  int tx = tid & 31, ty = tid >> 5;  // ty 0..7
#pragma unroll
  for (int j = 0; j < 32; j += 8)
    t[ty + j][tx] = in[(size_t)(k0 + ty + j) * N + n0 + tx];
  __syncthreads();
#pragma unroll
  for (int j = 0; j < 32; j += 8)
    out[(size_t)(n0 + ty + j) * K + k0 + tx] = __float2bfloat16(t[tx][ty + j]);
}

// ---------------- pooled = mean_P(param_seq) -> bf16 ----------------
__global__ void pool_mean(const float* __restrict__ ps,
                          __hip_bfloat16* __restrict__ pooled) {
  int idx = blockIdx.x * 256 + threadIdx.x;  // < 6400*768
  int row = idx / DD, c = idx - row * DD;
  float s = 0.f;
#pragma unroll
  for (int p = 0; p < 8; p++) s += ps[(size_t)(row * 8 + p) * DD + c];
  pooled[idx] = __float2bfloat16(s * 0.125f);
}

// ---------------- src = template + PE ----------------
__global__ void add_pe(const float* __restrict__ t, float* __restrict__ src) {
  int idx = blockIdx.x * 256 + threadIdx.x;
  int row = idx / DD, c = idx - row * DD;
  int srow = row % SS;
  int c2 = c & ~1;
  float ang = (float)srow * expf((float)c2 * (-LN10000 / (float)DD));
  float pe = (c & 1) ? cosf(ang) : sinf(ang);
  src[idx] = t[idx] + pe;
}

// ---------------- LayerNorm over rows of 768 ----------------
template <bool RESID, bool WB16>
__global__ void ln_row(const float* __restrict__ X, const float* __restrict__ R,
                       const float* __restrict__ g, const float* __restrict__ bb,
                       float* __restrict__ of, __hip_bfloat16* __restrict__ ob) {
  int row = blockIdx.x, tid = threadIdx.x;
  size_t base = (size_t)row * DD;
  float v[3];
#pragma unroll
  for (int i = 0; i < 3; i++) {
    int c = tid + i * 256;
    v[i] = X[base + c];
    if (RESID) v[i] += R[base + c];
  }
  __shared__ float sbuf[4];
  float s = block_sum256(v[0] + v[1] + v[2], sbuf);
  float mean = s * (1.0f / DD);
  float d0 = v[0] - mean, d1 = v[1] - mean, d2 = v[2] - mean;
  float ss = block_sum256(d0 * d0 + d1 * d1 + d2 * d2, sbuf);
  float rs = rsqrtf(ss * (1.0f / DD) + 1e-5f);
#pragma unroll
  for (int i = 0; i < 3; i++) {
    int c = tid + i * 256;
    float y = (v[i] - mean) * rs * g[c] + bb[c];
    of[base + c] = y;
    if (WB16) ob[base + c] = __float2bfloat16(y);
  }
}

// ---------------- param_bias[b,h,q,k] = pb.pb^T / sqrt(HD) ----------------
__global__ void param_bias_k(const float* __restrict__ penc,
                             float* __restrict__ pbias) {
  int bh = blockIdx.x;
  int b = bh >> 3, h = bh & 7;
  __shared__ float ps[SS][HD + 1];
  int tid = threadIdx.x;
  for (int i = tid; i < SS * HD; i += 256) {
    int s = i / HD, d = i - s * HD;
    ps[s][d] = penc[(size_t)(b * SS + s) * DD + h * HD + d];
  }
  __syncthreads();
  const float scale = 0.1020620726159658f;  // 1/sqrt(96)
  float* pb = pbias + (size_t)bh * SS * SS;
  for (int i = tid; i < SS * SS; i += 256) {
    int q = i / SS, k = i - q * SS;
    float acc = 0.f;
#pragma unroll 4
    for (int d = 0; d < HD; d++) acc += ps[q][d] * ps[k][d];
    pb[i] = acc * scale;
  }
}

// ---------------- attention part 1: probs = softmax(qq^T/sqrt(hd)+bias) ----------------
__global__ void attn_scores(const float* __restrict__ src,
                            const float* __restrict__ pbias,
                            float* __restrict__ probs) {
  int bh = blockIdx.x;
  int b = bh >> 3, h = bh & 7;
  __shared__ float qs[SS][HD + 1];
  int tid = threadIdx.x;
  for (int i = tid; i < SS * HD; i += 256) {
    int s = i / HD, d = i - s * HD;
    qs[s][d] = src[(size_t)(b * SS + s) * DD + h * HD + d];
  }
  __syncthreads();
  int wave = tid >> 6, lane = tid & 63;
  const float scale = 0.1020620726159658f;
  const float* pb = pbias + (size_t)bh * SS * SS;
  float* pr = probs + (size_t)bh * SS * SS;
  int k0 = lane, k1 = lane + 64;
  bool has1 = (k1 < SS);
  int k1c = has1 ? k1 : 0;
  for (int q = wave; q < SS; q += 4) {
    float a0 = 0.f, a1 = 0.f;
#pragma unroll 4
    for (int d = 0; d < HD; d++) {
      float qv = qs[q][d];
      a0 += qv * qs[k0][d];
      a1 += qv * qs[k1c][d];
    }
    a0 = a0 * scale + pb[q * SS + k0];
    a1 = has1 ? (a1 * scale + pb[q * SS + k1]) : -INFINITY;
    float m = fmaxf(a0, a1);
#pragma unroll
    for (int o = 32; o > 0; o >>= 1) m = fmaxf(m, __shfl_xor(m, o, 64));
    float e0 = expf(a0 - m);
    float e1 = has1 ? expf(a1 - m) : 0.f;
    float s = e0 + e1;
#pragma unroll
    for (int o = 32; o > 0; o >>= 1) s += __shfl_xor(s, o, 64);
    float inv = 1.0f / s;
    pr[q * SS + k0] = e0 * inv;
    if (has1) pr[q * SS + k1] = e1 * inv;
  }
}

// ---------------- attention part 2: out = probs @ q ----------------
__global__ void attn_out_k(const float* __restrict__ src,
                           const float* __restrict__ probs,
                           float* __restrict__ out) {
  int bh = blockIdx.x;
  int b = bh >> 3, h = bh & 7;
  __shared__ float qs[SS][HD];
  int tid = threadIdx.x;
  for (int i = tid; i < SS * HD; i += 256) {
    int s = i / HD, d = i - s * HD;
    qs[s][d] = src[(size_t)(b * SS + s) * DD + h * HD + d];
  }
  __syncthreads();
  const float* prb = probs + (size_t)bh * SS * SS;
  for (int i = tid; i < SS * HD; i += 256) {
    int q = i / HD, d = i - q * HD;
    const float* p = prb + q * SS;
    float acc = 0.f;
#pragma unroll 4
    for (int k = 0; k < SS; k++) acc += p[k] * qs[k][d];
    out[(size_t)(b * SS + q) * DD + h * HD + d] = acc;
  }
}

// ---------------- bf16 MFMA GEMM: C[M,N] = A[M,K] @ Bt[N,K]^T ----------------
// MODE 0: outf = C + bias            (fp32)
// MODE 1: outb = gelu(C + bias)      (bf16)
// MODE 2: outf = C + bias + resid    (fp32)
template <int MODE>
__launch_bounds__(256, 2)
__global__ void gemm_bt(const __hip_bfloat16* __restrict__ A,
                        const __hip_bfloat16* __restrict__ Bt,
                        const float* __restrict__ bias,
                        const float* __restrict__ resid,
                        float* __restrict__ outf,
                        __hip_bfloat16* __restrict__ outb,
                        int M, int N, int K) {
  constexpr int BM = 128, BN = 128, BK = 32;
  __shared__ __align__(16) __hip_bfloat16 As[BM * BK];
  __shared__ __align__(16) __hip_bfloat16 Bs[BN * BK];
  const int tid = threadIdx.x;
  const int wave = tid >> 6, lane = tid & 63;
  const int wr = (wave >> 1) * 64, wc = (wave & 1) * 64;
  const int m0 = blockIdx.y * BM, n0 = blockIdx.x * BN;
  const int r = lane & 15, q = lane >> 4;

  f32x4 acc[4][4] = {};

  for (int k0 = 0; k0 < K; k0 += BK) {
#pragma unroll
    for (int j = 0; j < 2; j++) {
      int li = tid + 256 * j;           // 0..511
      int row = li >> 2, cp = li & 3;   // 4 x 16B per 64B row
      ((float4*)As)[li] = *(const float4*)(A + (size_t)(m0 + row) * K + k0 + cp * 8);
      ((float4*)Bs)[li] = *(const float4*)(Bt + (size_t)(n0 + row) * K + k0 + cp * 8);
    }
    __syncthreads();
    bf16x8 af[4], bfr[4];
#pragma unroll
    for (int mi = 0; mi < 4; mi++)
      af[mi] = *(const bf16x8*)(As + (wr + mi * 16 + r) * BK + q * 8);
#pragma unroll
    for (int ni = 0; ni < 4; ni++)
      bfr[ni] = *(const bf16x8*)(Bs + (wc + ni * 16 + r) * BK + q * 8);
#pragma unroll
    for (int mi = 0; mi < 4; mi++)
#pragma unroll
      for (int ni = 0; ni < 4; ni++)
        acc[mi][ni] = __builtin_amdgcn_mfma_f32_16x16x32_bf16(af[mi], bfr[ni],
                                                              acc[mi][ni], 0, 0, 0);
    __syncthreads();
  }

  // epilogue: C layout col = lane&15, row = (lane>>4)*4 + reg
#pragma unroll
  for (int mi = 0; mi < 4; mi++) {
#pragma unroll
    for (int ni = 0; ni < 4; ni++) {
      int col = n0 + wc + ni * 16 + r;
      float bv = bias[col];
#pragma unroll
      for (int rg = 0; rg < 4; rg++) {
        int row = m0 + wr + mi * 16 + q * 4 + rg;
        size_t oidx = (size_t)row * N + col;
        float v = acc[mi][ni][rg] + bv;
        if constexpr (MODE == 2) v += resid[oidx];
        if constexpr (MODE == 1) {
          v = 0.5f * v * (1.0f + erff(v * 0.70710678118654752f));
          outb[oidx] = __float2bfloat16(v);
        } else {
          outf[oidx] = v;
        }
      }
    }
  }
}

// ---------------- final classifier: out[b,c] = x[b,:] . Wfc[:,c] + bfc ----------------
__global__ void classifier_k(const float* __restrict__ x,
                             const float* __restrict__ Wfc,
                             const float* __restrict__ bfc,
                             float* __restrict__ out) {
  int b = blockIdx.x, tid = threadIdx.x;
  const float* xb = x + (size_t)b * (SS * DD);
  float a0 = 0.f, a1 = 0.f;
  for (int i = tid; i < SS * DD; i += 256) {
    float xv = xb[i];
    a0 += xv * Wfc[2 * i];
    a1 += xv * Wfc[2 * i + 1];
  }
  __shared__ float sbuf[4];
  a0 = block_sum256(a0, sbuf);
  a1 = block_sum256(a1, sbuf);
  if (tid == 0) {
    out[2 * b] = a0 + bfc[0];
    out[2 * b + 1] = a1 + bfc[1];
  }
}

// ---------------- launcher ----------------
extern "C" void kernel_launch(void* const* d_in, const int* in_sizes, int n_in,
                              void* d_out, int out_size, void* d_ws, size_t ws_size,
                              hipStream_t stream) {
  const float* Tmpl = (const float*)d_in[0];
  const float* Pseq = (const float*)d_in[1];
  const float* Wc   = (const float*)d_in[2];
  const float* bc   = (const float*)d_in[3];
  const float* gp   = (const float*)d_in[4];
  const float* bp   = (const float*)d_in[5];
  const float* W1   = (const float*)d_in[6];
  const float* b1   = (const float*)d_in[7];
  const float* W2   = (const float*)d_in[8];
  const float* b2   = (const float*)d_in[9];
  const float* g1   = (const float*)d_in[10];
  const float* bn1  = (const float*)d_in[11];
  const float* g2   = (const float*)d_in[12];
  const float* bn2  = (const float*)d_in[13];
  const float* Wfc  = (const float*)d_in[14];
  const float* bfc  = (const float*)d_in[15];
  float* out = (float*)d_out;
  (void)in_sizes; (void)n_in; (void)out_size; (void)ws_size;

  char* ws = (char*)d_ws;
  size_t off = 0;
  auto alloc = [&](size_t n) { size_t o = off; off += (n + 255) & ~(size_t)255; return o; };

  __hip_bfloat16* Wct = (__hip_bfloat16*)(ws + alloc((size_t)768 * 768 * 2));
  __hip_bfloat16* W1t = (__hip_bfloat16*)(ws + alloc((size_t)768 * 3072 * 2));
  __hip_bfloat16* W2t = (__hip_bfloat16*)(ws + alloc((size_t)3072 * 768 * 2));
  size_t h1_off = alloc((size_t)ROWS * FF_ * 2);
  __hip_bfloat16* h1 = (__hip_bfloat16*)(ws + h1_off);
  float* param_enc = (float*)(ws + h1_off);            // alias: dead before h1 live
  size_t slb_off = alloc((size_t)ROWS * DD * 2);
  __hip_bfloat16* src_ln_bf = (__hip_bfloat16*)(ws + slb_off);
  __hip_bfloat16* pooled = (__hip_bfloat16*)(ws + slb_off);  // alias: dead before src_ln_bf live
  size_t ao_off = alloc((size_t)ROWS * DD * 4);
  float* attn_out_b = (float*)(ws + ao_off);
  float* pe_lin = (float*)(ws + ao_off);               // alias: dead before attn_out live
  float* pbias = (float*)(ws + alloc((size_t)512 * SS * SS * 4));
  float* src = (float*)(ws + alloc((size_t)ROWS * DD * 4));
  float* src_ln = (float*)(ws + alloc((size_t)ROWS * DD * 4));
  size_t pz_off = alloc((size_t)512 * SS * SS * 4);
  float* probs = (float*)(ws + pz_off);
  float* z = (float*)(ws + pz_off);                    // alias: probs dead before z live

  // ---- layer-invariant precompute ----
  convert_transpose<<<dim3(768 / 32, 768 / 32), 256, 0, stream>>>(Wc, Wct, 768, 768);
  convert_transpose<<<dim3(3072 / 32, 768 / 32), 256, 0, stream>>>(W1, W1t, 768, 3072);
  convert_transpose<<<dim3(768 / 32, 3072 / 32), 256, 0, stream>>>(W2, W2t, 3072, 768);
  pool_mean<<<ROWS * DD / 256, 256, 0, stream>>>(Pseq, pooled);
  gemm_bt<0><<<dim3(DD / 128, ROWS / 128), 256, 0, stream>>>(
      pooled, Wct, bc, nullptr, pe_lin, nullptr, ROWS, DD, 768);
  ln_row<false, false><<<ROWS, 256, 0, stream>>>(pe_lin, nullptr, gp, bp, param_enc, nullptr);
  param_bias_k<<<512, 256, 0, stream>>>(param_enc, pbias);
  add_pe<<<ROWS * DD / 256, 256, 0, stream>>>(Tmpl, src);

  // ---- 4 shared layers ----
  for (int l = 0; l < 4; ++l) {
    attn_scores<<<512, 256, 0, stream>>>(src, pbias, probs);
    attn_out_k<<<512, 256, 0, stream>>>(src, probs, attn_out_b);
    ln_row<true, true><<<ROWS, 256, 0, stream>>>(attn_out_b, src, g1, bn1, src_ln, src_ln_bf);
    gemm_bt<1><<<dim3(FF_ / 128, ROWS / 128), 256, 0, stream>>>(
        src_ln_bf, W1t, b1, nullptr, nullptr, h1, ROWS, FF_, DD);
    gemm_bt<2><<<dim3(DD / 128, ROWS / 128), 256, 0, stream>>>(
        h1, W2t, b2, src_ln, z, nullptr, ROWS, DD, FF_);
    ln_row<false, false><<<ROWS, 256, 0, stream>>>(z, nullptr, g2, bn2, src, nullptr);
  }

  classifier_k<<<BB, 256, 0, stream>>>(src, Wfc, bfc, out);
}

// Round 2
// 1714.230 us; speedup vs baseline: 1.1943x; 1.1943x over previous
//
#include <hip/hip_runtime.h>
#include <hip/hip_bf16.h>
#include <math.h>

// Model: B=64,S=100,D=768,H=8,P=8,FF=3072,HD=96, 4 shared layers.
//  - param path (pooled -> proj -> LN -> param_bias) computed ONCE (layer-shared).
//  - big GEMMs in bf16 MFMA (16x16x32), 128x128 tile, fp32 accumulate.
//  - attention fused per (b,h): scores+softmax+PV, probs live in LDS only (R1).

typedef __attribute__((ext_vector_type(8))) short bf16x8;
typedef __attribute__((ext_vector_type(4))) float f32x4;

#define BB 64
#define SS 100
#define DD 768
#define HH 8
#define HD 96
#define FF_ 3072
#define ROWS 6400           // B*S
#define LN10000 9.210340371976184f

// ---------------- block-wide sum over 256 threads ----------------
__device__ __forceinline__ float block_sum256(float v, float* sbuf) {
#pragma unroll
  for (int o = 32; o > 0; o >>= 1) v += __shfl_xor(v, o, 64);
  int tid = threadIdx.x;
  __syncthreads();
  if ((tid & 63) == 0) sbuf[tid >> 6] = v;
  __syncthreads();
  return sbuf[0] + sbuf[1] + sbuf[2] + sbuf[3];
}

// ---------------- fp32 [K,N] -> bf16 [N,K] transpose-convert ----------------
__global__ void convert_transpose(const float* __restrict__ in,
                                  __hip_bfloat16* __restrict__ out,
                                  int K, int N) {
  __shared__ float t[32][33];
  int n0 = blockIdx.x * 32, k0 = blockIdx.y * 32;
  int tid = threadIdx.x;
  int tx = tid & 31, ty = tid >> 5;  // ty 0..7
#pragma unroll
  for (int j = 0; j < 32; j += 8)
    t[ty + j][tx] = in[(size_t)(k0 + ty + j) * N + n0 + tx];
  __syncthreads();
#pragma unroll
  for (int j = 0; j < 32; j += 8)
    out[(size_t)(n0 + ty + j) * K + k0 + tx] = __float2bfloat16(t[tx][ty + j]);
}

// ---------------- pooled = mean_P(param_seq) -> bf16 ----------------
__global__ void pool_mean(const float* __restrict__ ps,
                          __hip_bfloat16* __restrict__ pooled) {
  int idx = blockIdx.x * 256 + threadIdx.x;  // < 6400*768
  int row = idx / DD, c = idx - row * DD;
  float s = 0.f;
#pragma unroll
  for (int p = 0; p < 8; p++) s += ps[(size_t)(row * 8 + p) * DD + c];
  pooled[idx] = __float2bfloat16(s * 0.125f);
}

// ---------------- src = template + PE ----------------
__global__ void add_pe(const float* __restrict__ t, float* __restrict__ src) {
  int idx = blockIdx.x * 256 + threadIdx.x;
  int row = idx / DD, c = idx - row * DD;
  int srow = row % SS;
  int c2 = c & ~1;
  float ang = (float)srow * expf((float)c2 * (-LN10000 / (float)DD));
  float pe = (c & 1) ? cosf(ang) : sinf(ang);
  src[idx] = t[idx] + pe;
}

// ---------------- LayerNorm over rows of 768 ----------------
template <bool RESID, bool WB16>
__global__ void ln_row(const float* __restrict__ X, const float* __restrict__ R,
                       const float* __restrict__ g, const float* __restrict__ bb,
                       float* __restrict__ of, __hip_bfloat16* __restrict__ ob) {
  int row = blockIdx.x, tid = threadIdx.x;
  size_t base = (size_t)row * DD;
  float v[3];
#pragma unroll
  for (int i = 0; i < 3; i++) {
    int c = tid + i * 256;
    v[i] = X[base + c];
    if (RESID) v[i] += R[base + c];
  }
  __shared__ float sbuf[4];
  float s = block_sum256(v[0] + v[1] + v[2], sbuf);
  float mean = s * (1.0f / DD);
  float d0 = v[0] - mean, d1 = v[1] - mean, d2 = v[2] - mean;
  float ss = block_sum256(d0 * d0 + d1 * d1 + d2 * d2, sbuf);
  float rs = rsqrtf(ss * (1.0f / DD) + 1e-5f);
#pragma unroll
  for (int i = 0; i < 3; i++) {
    int c = tid + i * 256;
    float y = (v[i] - mean) * rs * g[c] + bb[c];
    of[base + c] = y;
    if (WB16) ob[base + c] = __float2bfloat16(y);
  }
}

// ---------------- param_bias[b,h,q,k] = pb.pb^T / sqrt(HD) ----------------
__global__ void param_bias_k(const float* __restrict__ penc,
                             float* __restrict__ pbias) {
  int bh = blockIdx.x;
  int b = bh >> 3, h = bh & 7;
  __shared__ float ps[SS][HD + 1];
  int tid = threadIdx.x;
  for (int i = tid; i < SS * HD; i += 256) {
    int s = i / HD, d = i - s * HD;
    ps[s][d] = penc[(size_t)(b * SS + s) * DD + h * HD + d];
  }
  __syncthreads();
  const float scale = 0.1020620726159658f;  // 1/sqrt(96)
  float* pb = pbias + (size_t)bh * SS * SS;
  for (int i = tid; i < SS * SS; i += 256) {
    int q = i / SS, k = i - q * SS;
    float acc = 0.f;
#pragma unroll 4
    for (int d = 0; d < HD; d++) acc += ps[q][d] * ps[k][d];
    pb[i] = acc * scale;
  }
}

// ---------------- fused attention: scores+softmax+PV, probs in LDS ----------------
__launch_bounds__(256, 2)
__global__ void attn_fused(const float* __restrict__ src,
                           const float* __restrict__ pbias,
                           float* __restrict__ out) {
  int bh = blockIdx.x;
  int b = bh >> 3, h = bh & 7;
  __shared__ float qs[SS][HD + 1];                 // 38.8 KB
  __shared__ __hip_bfloat16 pr[SS][SS + 4];        // 20.8 KB
  int tid = threadIdx.x;
  for (int i = tid; i < SS * HD; i += 256) {
    int s = i / HD, d = i - s * HD;
    qs[s][d] = src[(size_t)(b * SS + s) * DD + h * HD + d];
  }
  __syncthreads();

  // ---- scores + softmax (wave handles rows q = wave + 4*i; lanes = cols) ----
  int wave = tid >> 6, lane = tid & 63;
  const float scale = 0.1020620726159658f;         // 1/sqrt(96)
  const float* pb = pbias + (size_t)bh * SS * SS;
  int k0 = lane, k1 = lane + 64;
  bool has1 = (k1 < SS);
  int k1c = has1 ? k1 : 0;
  for (int q = wave; q < SS; q += 4) {
    float a0 = 0.f, a1 = 0.f;
#pragma unroll 4
    for (int d = 0; d < HD; d++) {
      float qv = qs[q][d];
      a0 += qv * qs[k0][d];
      a1 += qv * qs[k1c][d];
    }
    a0 = a0 * scale + pb[q * SS + k0];
    a1 = has1 ? (a1 * scale + pb[q * SS + k1]) : -INFINITY;
    float m = fmaxf(a0, a1);
#pragma unroll
    for (int o = 32; o > 0; o >>= 1) m = fmaxf(m, __shfl_xor(m, o, 64));
    float e0 = expf(a0 - m);
    float e1 = has1 ? expf(a1 - m) : 0.f;
    float s = e0 + e1;
#pragma unroll
    for (int o = 32; o > 0; o >>= 1) s += __shfl_xor(s, o, 64);
    float inv = 1.0f / s;
    pr[q][k0] = __float2bfloat16(e0 * inv);
    if (has1) pr[q][k1] = __float2bfloat16(e1 * inv);
  }
  __syncthreads();

  // ---- PV: out[q][d] = sum_k pr[q][k] * qs[k][d] ----
  for (int i = tid; i < SS * HD; i += 256) {
    int q = i / HD, d = i - q * HD;
    float acc = 0.f;
#pragma unroll 4
    for (int k = 0; k < SS; k++) acc += __bfloat162float(pr[q][k]) * qs[k][d];
    out[(size_t)(b * SS + q) * DD + h * HD + d] = acc;
  }
}

// ---------------- bf16 MFMA GEMM: C[M,N] = A[M,K] @ Bt[N,K]^T ----------------
// MODE 0: outf = C + bias            (fp32)
// MODE 1: outb = gelu(C + bias)      (bf16)
// MODE 2: outf = C + bias + resid    (fp32)
template <int MODE>
__launch_bounds__(256, 2)
__global__ void gemm_bt(const __hip_bfloat16* __restrict__ A,
                        const __hip_bfloat16* __restrict__ Bt,
                        const float* __restrict__ bias,
                        const float* __restrict__ resid,
                        float* __restrict__ outf,
                        __hip_bfloat16* __restrict__ outb,
                        int M, int N, int K) {
  constexpr int BM = 128, BN = 128, BK = 32;
  __shared__ __align__(16) __hip_bfloat16 As[BM * BK];
  __shared__ __align__(16) __hip_bfloat16 Bs[BN * BK];
  const int tid = threadIdx.x;
  const int wave = tid >> 6, lane = tid & 63;
  const int wr = (wave >> 1) * 64, wc = (wave & 1) * 64;
  const int m0 = blockIdx.y * BM, n0 = blockIdx.x * BN;
  const int r = lane & 15, q = lane >> 4;

  f32x4 acc[4][4] = {};

  for (int k0 = 0; k0 < K; k0 += BK) {
#pragma unroll
    for (int j = 0; j < 2; j++) {
      int li = tid + 256 * j;           // 0..511
      int row = li >> 2, cp = li & 3;   // 4 x 16B per 64B row
      ((float4*)As)[li] = *(const float4*)(A + (size_t)(m0 + row) * K + k0 + cp * 8);
      ((float4*)Bs)[li] = *(const float4*)(Bt + (size_t)(n0 + row) * K + k0 + cp * 8);
    }
    __syncthreads();
    bf16x8 af[4], bfr[4];
#pragma unroll
    for (int mi = 0; mi < 4; mi++)
      af[mi] = *(const bf16x8*)(As + (wr + mi * 16 + r) * BK + q * 8);
#pragma unroll
    for (int ni = 0; ni < 4; ni++)
      bfr[ni] = *(const bf16x8*)(Bs + (wc + ni * 16 + r) * BK + q * 8);
#pragma unroll
    for (int mi = 0; mi < 4; mi++)
#pragma unroll
      for (int ni = 0; ni < 4; ni++)
        acc[mi][ni] = __builtin_amdgcn_mfma_f32_16x16x32_bf16(af[mi], bfr[ni],
                                                              acc[mi][ni], 0, 0, 0);
    __syncthreads();
  }

  // epilogue: C layout col = lane&15, row = (lane>>4)*4 + reg
#pragma unroll
  for (int mi = 0; mi < 4; mi++) {
#pragma unroll
    for (int ni = 0; ni < 4; ni++) {
      int col = n0 + wc + ni * 16 + r;
      float bv = bias[col];
#pragma unroll
      for (int rg = 0; rg < 4; rg++) {
        int row = m0 + wr + mi * 16 + q * 4 + rg;
        size_t oidx = (size_t)row * N + col;
        float v = acc[mi][ni][rg] + bv;
        if constexpr (MODE == 2) v += resid[oidx];
        if constexpr (MODE == 1) {
          v = 0.5f * v * (1.0f + erff(v * 0.70710678118654752f));
          outb[oidx] = __float2bfloat16(v);
        } else {
          outf[oidx] = v;
        }
      }
    }
  }
}

// ---------------- final classifier: out[b,c] = x[b,:] . Wfc[:,c] + bfc ----------------
__global__ void classifier_k(const float* __restrict__ x,
                             const float* __restrict__ Wfc,
                             const float* __restrict__ bfc,
                             float* __restrict__ out) {
  int b = blockIdx.x, tid = threadIdx.x;
  const float* xb = x + (size_t)b * (SS * DD);
  float a0 = 0.f, a1 = 0.f;
  for (int i = tid; i < SS * DD; i += 256) {
    float xv = xb[i];
    a0 += xv * Wfc[2 * i];
    a1 += xv * Wfc[2 * i + 1];
  }
  __shared__ float sbuf[4];
  a0 = block_sum256(a0, sbuf);
  a1 = block_sum256(a1, sbuf);
  if (tid == 0) {
    out[2 * b] = a0 + bfc[0];
    out[2 * b + 1] = a1 + bfc[1];
  }
}

// ---------------- launcher ----------------
extern "C" void kernel_launch(void* const* d_in, const int* in_sizes, int n_in,
                              void* d_out, int out_size, void* d_ws, size_t ws_size,
                              hipStream_t stream) {
  const float* Tmpl = (const float*)d_in[0];
  const float* Pseq = (const float*)d_in[1];
  const float* Wc   = (const float*)d_in[2];
  const float* bc   = (const float*)d_in[3];
  const float* gp   = (const float*)d_in[4];
  const float* bp   = (const float*)d_in[5];
  const float* W1   = (const float*)d_in[6];
  const float* b1   = (const float*)d_in[7];
  const float* W2   = (const float*)d_in[8];
  const float* b2   = (const float*)d_in[9];
  const float* g1   = (const float*)d_in[10];
  const float* bn1  = (const float*)d_in[11];
  const float* g2   = (const float*)d_in[12];
  const float* bn2  = (const float*)d_in[13];
  const float* Wfc  = (const float*)d_in[14];
  const float* bfc  = (const float*)d_in[15];
  float* out = (float*)d_out;
  (void)in_sizes; (void)n_in; (void)out_size; (void)ws_size;

  char* ws = (char*)d_ws;
  size_t off = 0;
  auto alloc = [&](size_t n) { size_t o = off; off += (n + 255) & ~(size_t)255; return o; };

  __hip_bfloat16* Wct = (__hip_bfloat16*)(ws + alloc((size_t)768 * 768 * 2));
  __hip_bfloat16* W1t = (__hip_bfloat16*)(ws + alloc((size_t)768 * 3072 * 2));
  __hip_bfloat16* W2t = (__hip_bfloat16*)(ws + alloc((size_t)3072 * 768 * 2));
  size_t h1_off = alloc((size_t)ROWS * FF_ * 2);
  __hip_bfloat16* h1 = (__hip_bfloat16*)(ws + h1_off);
  float* param_enc = (float*)(ws + h1_off);            // alias: dead before h1 live
  size_t slb_off = alloc((size_t)ROWS * DD * 2);
  __hip_bfloat16* src_ln_bf = (__hip_bfloat16*)(ws + slb_off);
  __hip_bfloat16* pooled = (__hip_bfloat16*)(ws + slb_off);  // alias: dead before src_ln_bf live
  size_t ao_off = alloc((size_t)ROWS * DD * 4);
  float* attn_out_b = (float*)(ws + ao_off);
  float* pe_lin = (float*)(ws + ao_off);               // alias: dead before attn_out live
  float* pbias = (float*)(ws + alloc((size_t)512 * SS * SS * 4));
  float* src = (float*)(ws + alloc((size_t)ROWS * DD * 4));
  float* src_ln = (float*)(ws + alloc((size_t)ROWS * DD * 4));
  float* z = (float*)(ws + alloc((size_t)ROWS * DD * 4));

  // ---- layer-invariant precompute ----
  convert_transpose<<<dim3(768 / 32, 768 / 32), 256, 0, stream>>>(Wc, Wct, 768, 768);
  convert_transpose<<<dim3(3072 / 32, 768 / 32), 256, 0, stream>>>(W1, W1t, 768, 3072);
  convert_transpose<<<dim3(768 / 32, 3072 / 32), 256, 0, stream>>>(W2, W2t, 3072, 768);
  pool_mean<<<ROWS * DD / 256, 256, 0, stream>>>(Pseq, pooled);
  gemm_bt<0><<<dim3(DD / 128, ROWS / 128), 256, 0, stream>>>(
      pooled, Wct, bc, nullptr, pe_lin, nullptr, ROWS, DD, 768);
  ln_row<false, false><<<ROWS, 256, 0, stream>>>(pe_lin, nullptr, gp, bp, param_enc, nullptr);
  param_bias_k<<<512, 256, 0, stream>>>(param_enc, pbias);
  add_pe<<<ROWS * DD / 256, 256, 0, stream>>>(Tmpl, src);

  // ---- 4 shared layers ----
  for (int l = 0; l < 4; ++l) {
    attn_fused<<<512, 256, 0, stream>>>(src, pbias, attn_out_b);
    ln_row<true, true><<<ROWS, 256, 0, stream>>>(attn_out_b, src, g1, bn1, src_ln, src_ln_bf);
    gemm_bt<1><<<dim3(FF_ / 128, ROWS / 128), 256, 0, stream>>>(
        src_ln_bf, W1t, b1, nullptr, nullptr, h1, ROWS, FF_, DD);
    gemm_bt<2><<<dim3(DD / 128, ROWS / 128), 256, 0, stream>>>(
        h1, W2t, b2, src_ln, z, nullptr, ROWS, DD, FF_);
    ln_row<false, false><<<ROWS, 256, 0, stream>>>(z, nullptr, g2, bn2, src, nullptr);
  }

  classifier_k<<<BB, 256, 0, stream>>>(src, Wfc, bfc, out);
}

// Round 3
// 1202.740 us; speedup vs baseline: 1.7022x; 1.4253x over previous
//
#include <hip/hip_runtime.h>
#include <hip/hip_bf16.h>
#include <math.h>

// Model: B=64,S=100,D=768,H=8,P=8,FF=3072,HD=96, 4 shared layers.
//  - param path computed ONCE (layer-shared).
//  - big GEMMs: bf16 MFMA 128x128 tile + global_load_lds width-16 staging (R2).
//  - attention per (b,h): MFMA scores (pbias as C-init) + reg-softmax + MFMA PV (R2).

typedef __attribute__((ext_vector_type(8))) short bf16x8;
typedef __attribute__((ext_vector_type(4))) float f32x4;

#define BB 64
#define SS 100
#define DD 768
#define HH 8
#define HD 96
#define FF_ 3072
#define ROWS 6400           // B*S
#define LN10000 9.210340371976184f

__device__ __forceinline__ void async_copy16(void* lds_dst, const void* gsrc) {
  __builtin_amdgcn_global_load_lds(
      (const __attribute__((address_space(1))) void*)gsrc,
      (__attribute__((address_space(3))) void*)lds_dst, 16, 0, 0);
}

// ---------------- block-wide sum over 256 threads ----------------
__device__ __forceinline__ float block_sum256(float v, float* sbuf) {
#pragma unroll
  for (int o = 32; o > 0; o >>= 1) v += __shfl_xor(v, o, 64);
  int tid = threadIdx.x;
  __syncthreads();
  if ((tid & 63) == 0) sbuf[tid >> 6] = v;
  __syncthreads();
  return sbuf[0] + sbuf[1] + sbuf[2] + sbuf[3];
}

// ---------------- fp32 [K,N] -> bf16 [N,K] transpose-convert ----------------
__global__ void convert_transpose(const float* __restrict__ in,
                                  __hip_bfloat16* __restrict__ out,
                                  int K, int N) {
  __shared__ float t[32][33];
  int n0 = blockIdx.x * 32, k0 = blockIdx.y * 32;
  int tid = threadIdx.x;
  int tx = tid & 31, ty = tid >> 5;  // ty 0..7
#pragma unroll
  for (int j = 0; j < 32; j += 8)
    t[ty + j][tx] = in[(size_t)(k0 + ty + j) * N + n0 + tx];
  __syncthreads();
#pragma unroll
  for (int j = 0; j < 32; j += 8)
    out[(size_t)(n0 + ty + j) * K + k0 + tx] = __float2bfloat16(t[tx][ty + j]);
}

// ---------------- pooled = mean_P(param_seq) -> bf16 ----------------
__global__ void pool_mean(const float* __restrict__ ps,
                          __hip_bfloat16* __restrict__ pooled) {
  int idx = blockIdx.x * 256 + threadIdx.x;  // < 6400*768
  int row = idx / DD, c = idx - row * DD;
  float s = 0.f;
#pragma unroll
  for (int p = 0; p < 8; p++) s += ps[(size_t)(row * 8 + p) * DD + c];
  pooled[idx] = __float2bfloat16(s * 0.125f);
}

// ---------------- src = template + PE ----------------
__global__ void add_pe(const float* __restrict__ t, float* __restrict__ src) {
  int idx = blockIdx.x * 256 + threadIdx.x;
  int row = idx / DD, c = idx - row * DD;
  int srow = row % SS;
  int c2 = c & ~1;
  float ang = (float)srow * expf((float)c2 * (-LN10000 / (float)DD));
  float pe = (c & 1) ? cosf(ang) : sinf(ang);
  src[idx] = t[idx] + pe;
}

// ---------------- LayerNorm over rows of 768 ----------------
template <bool RESID, bool WB16>
__global__ void ln_row(const float* __restrict__ X, const float* __restrict__ R,
                       const float* __restrict__ g, const float* __restrict__ bb,
                       float* __restrict__ of, __hip_bfloat16* __restrict__ ob) {
  int row = blockIdx.x, tid = threadIdx.x;
  size_t base = (size_t)row * DD;
  float v[3];
#pragma unroll
  for (int i = 0; i < 3; i++) {
    int c = tid + i * 256;
    v[i] = X[base + c];
    if (RESID) v[i] += R[base + c];
  }
  __shared__ float sbuf[4];
  float s = block_sum256(v[0] + v[1] + v[2], sbuf);
  float mean = s * (1.0f / DD);
  float d0 = v[0] - mean, d1 = v[1] - mean, d2 = v[2] - mean;
  float ss = block_sum256(d0 * d0 + d1 * d1 + d2 * d2, sbuf);
  float rs = rsqrtf(ss * (1.0f / DD) + 1e-5f);
#pragma unroll
  for (int i = 0; i < 3; i++) {
    int c = tid + i * 256;
    float y = (v[i] - mean) * rs * g[c] + bb[c];
    of[base + c] = y;
    if (WB16) ob[base + c] = __float2bfloat16(y);
  }
}

// ---------------- param_bias[b,h,q,k] = pb.pb^T / sqrt(HD) ----------------
__global__ void param_bias_k(const float* __restrict__ penc,
                             float* __restrict__ pbias) {
  int bh = blockIdx.x;
  int b = bh >> 3, h = bh & 7;
  __shared__ float ps[SS][HD + 1];
  int tid = threadIdx.x;
  for (int i = tid; i < SS * HD; i += 256) {
    int s = i / HD, d = i - s * HD;
    ps[s][d] = penc[(size_t)(b * SS + s) * DD + h * HD + d];
  }
  __syncthreads();
  const float scale = 0.1020620726159658f;  // 1/sqrt(96)
  float* pb = pbias + (size_t)bh * SS * SS;
  for (int i = tid; i < SS * SS; i += 256) {
    int q = i / SS, k = i - q * SS;
    float acc = 0.f;
#pragma unroll 4
    for (int d = 0; d < HD; d++) acc += ps[q][d] * ps[k][d];
    pb[i] = acc * scale;
  }
}

// ---------------- fused MFMA attention per (b,h) ----------------
// scores: S[128x128] = (c*Q)(c*Q)^T + pbias (C-init), c = 96^-1/4, K=96
// softmax: fp32 in registers, cross-wave via 1KB LDS
// PV: out^T[96x128] = Qt @ P^T (A=Qt rows d, B=P rows q), K=128
__launch_bounds__(256, 2)
__global__ void attn_fused_mfma(const float* __restrict__ src,
                                const float* __restrict__ pbias,
                                float* __restrict__ out) {
  __shared__ __align__(16) char umem[128 * 136 * 2];  // Qs[128][104] then Ps[128][136]
  __shared__ __align__(16) __hip_bfloat16 Qt[96][136];
  __shared__ float redm[2][128];
  __shared__ float reds[2][128];
  __hip_bfloat16 (*Qs)[104] = (__hip_bfloat16 (*)[104])umem;
  __hip_bfloat16 (*Ps)[136] = (__hip_bfloat16 (*)[136])umem;

  const int bh = blockIdx.x;
  const int b = bh >> 3, h = bh & 7;
  const int tid = threadIdx.x;
  const int wave = tid >> 6, lane = tid & 63;
  const int r = lane & 15, quad = lane >> 4;
  const int q8 = quad * 8;
  const int wr = (wave >> 1) * 64, wc = (wave & 1) * 64;

  // ---- stage Q (scaled for scores) and Qt (unscaled, for PV) ----
  const float sroot = rsqrtf(9.79795897113f);  // 96^(-1/4)
  for (int i = tid; i < SS * HD; i += 256) {
    int s = i / HD, d = i - s * HD;
    float v = src[(size_t)(b * SS + s) * DD + h * HD + d];
    Qs[s][d] = __float2bfloat16(v * sroot);
    Qt[d][s] = __float2bfloat16(v);
  }
  for (int i = tid; i < 28 * HD; i += 256) {  // zero pads
    int s = i / HD, d = i - s * HD;           // s in 0..27
    Qs[100 + s][d] = __float2bfloat16(0.f);
    Qt[d][100 + s] = __float2bfloat16(0.f);
  }

  // ---- acc init = pbias fragment ----
  const float* pb = pbias + (size_t)bh * SS * SS;
  bool cv[4]; int cols[4];
#pragma unroll
  for (int ni = 0; ni < 4; ni++) { cols[ni] = wc + ni * 16 + r; cv[ni] = cols[ni] < SS; }
  f32x4 acc[4][4];
#pragma unroll
  for (int mi = 0; mi < 4; mi++)
#pragma unroll
    for (int rg = 0; rg < 4; rg++) {
      int row = wr + mi * 16 + quad * 4 + rg;
#pragma unroll
      for (int ni = 0; ni < 4; ni++)
        acc[mi][ni][rg] = (row < SS && cv[ni]) ? pb[row * SS + cols[ni]] : 0.f;
    }
  __syncthreads();

  // ---- scores MFMA (reads Qs as both A and B) ----
#pragma unroll
  for (int k0 = 0; k0 < HD; k0 += 32) {
    bf16x8 af[4], bfv[4];
#pragma unroll
    for (int mi = 0; mi < 4; mi++)
      af[mi] = *(const bf16x8*)&Qs[wr + mi * 16 + r][k0 + q8];
#pragma unroll
    for (int ni = 0; ni < 4; ni++)
      bfv[ni] = *(const bf16x8*)&Qs[wc + ni * 16 + r][k0 + q8];
#pragma unroll
    for (int mi = 0; mi < 4; mi++)
#pragma unroll
      for (int ni = 0; ni < 4; ni++)
        acc[mi][ni] = __builtin_amdgcn_mfma_f32_16x16x32_bf16(af[mi], bfv[ni],
                                                              acc[mi][ni], 0, 0, 0);
  }

  // ---- softmax: row max (in-reg + cross-wave) ----
  float mx[4][4];
#pragma unroll
  for (int mi = 0; mi < 4; mi++)
#pragma unroll
    for (int rg = 0; rg < 4; rg++) {
      float m = -1e30f;
#pragma unroll
      for (int ni = 0; ni < 4; ni++)
        if (cv[ni]) m = fmaxf(m, acc[mi][ni][rg]);
#pragma unroll
      for (int o = 1; o < 16; o <<= 1) m = fmaxf(m, __shfl_xor(m, o, 64));
      mx[mi][rg] = m;
    }
  if (r == 0) {
#pragma unroll
    for (int mi = 0; mi < 4; mi++)
#pragma unroll
      for (int rg = 0; rg < 4; rg++)
        redm[wave & 1][wr + mi * 16 + quad * 4 + rg] = mx[mi][rg];
  }
  __syncthreads();  // MFMA Qs reads complete + redm visible

  // ---- exp + row sum ----
#pragma unroll
  for (int mi = 0; mi < 4; mi++)
#pragma unroll
    for (int rg = 0; rg < 4; rg++) {
      int row = wr + mi * 16 + quad * 4 + rg;
      float rmax = fmaxf(redm[0][row], redm[1][row]);
      float s = 0.f;
#pragma unroll
      for (int ni = 0; ni < 4; ni++) {
        float e = cv[ni] ? __expf(acc[mi][ni][rg] - rmax) : 0.f;
        acc[mi][ni][rg] = e;
        s += e;
      }
#pragma unroll
      for (int o = 1; o < 16; o <<= 1) s += __shfl_xor(s, o, 64);
      if (r == 0) reds[wave & 1][row] = s;
    }
  __syncthreads();

  // ---- normalize, write P bf16 into union (Qs dead) ----
#pragma unroll
  for (int mi = 0; mi < 4; mi++)
#pragma unroll
    for (int rg = 0; rg < 4; rg++) {
      int row = wr + mi * 16 + quad * 4 + rg;
      float inv = 1.0f / (reds[0][row] + reds[1][row]);
#pragma unroll
      for (int ni = 0; ni < 4; ni++)
        Ps[row][cols[ni]] = __float2bfloat16(acc[mi][ni][rg] * inv);
    }
  __syncthreads();

  // ---- PV: out^T[d][q], A=Qt (M=96), B=Ps (N=128), K=128 ----
  const int wr2 = (wave >> 1) * 48;
  f32x4 po[3][4] = {};
#pragma unroll
  for (int kk = 0; kk < 128; kk += 32) {
    bf16x8 aq[3], bp[4];
#pragma unroll
    for (int mi = 0; mi < 3; mi++)
      aq[mi] = *(const bf16x8*)&Qt[wr2 + mi * 16 + r][kk + q8];
#pragma unroll
    for (int ni = 0; ni < 4; ni++)
      bp[ni] = *(const bf16x8*)&Ps[wc + ni * 16 + r][kk + q8];
#pragma unroll
    for (int mi = 0; mi < 3; mi++)
#pragma unroll
      for (int ni = 0; ni < 4; ni++)
        po[mi][ni] = __builtin_amdgcn_mfma_f32_16x16x32_bf16(aq[mi], bp[ni],
                                                             po[mi][ni], 0, 0, 0);
  }
#pragma unroll
  for (int mi = 0; mi < 3; mi++)
#pragma unroll
    for (int ni = 0; ni < 4; ni++) {
      int qcol = wc + ni * 16 + r;
      if (qcol < SS) {
#pragma unroll
        for (int rg = 0; rg < 4; rg++) {
          int d = wr2 + mi * 16 + quad * 4 + rg;
          out[(size_t)(b * SS + qcol) * DD + h * HD + d] = po[mi][ni][rg];
        }
      }
    }
}

// ---------------- bf16 MFMA GEMM: C[M,N] = A[M,K] @ Bt[N,K]^T ----------------
// MODE 0: outf = C + bias            (fp32)
// MODE 1: outb = gelu(C + bias)      (bf16)
// MODE 2: outf = C + bias + resid    (fp32)
template <int MODE>
__launch_bounds__(256, 2)
__global__ void gemm_bt(const __hip_bfloat16* __restrict__ A,
                        const __hip_bfloat16* __restrict__ Bt,
                        const float* __restrict__ bias,
                        const float* __restrict__ resid,
                        float* __restrict__ outf,
                        __hip_bfloat16* __restrict__ outb,
                        int M, int N, int K) {
  constexpr int BM = 128, BN = 128, BK = 32;
  __shared__ __align__(16) __hip_bfloat16 As[BM * BK];
  __shared__ __align__(16) __hip_bfloat16 Bs[BN * BK];
  const int tid = threadIdx.x;
  const int wave = tid >> 6, lane = tid & 63;
  const int wr = (wave >> 1) * 64, wc = (wave & 1) * 64;
  const int m0 = blockIdx.y * BM, n0 = blockIdx.x * BN;
  const int r = lane & 15, q = lane >> 4;

  f32x4 acc[4][4] = {};

  for (int k0 = 0; k0 < K; k0 += BK) {
#pragma unroll
    for (int j = 0; j < 2; j++) {
      int li = tid + 256 * j;           // 0..511
      int row = li >> 2, cp = li & 3;   // 4 x 16B per 64B row
      async_copy16(As + li * 8, A + (size_t)(m0 + row) * K + k0 + cp * 8);
      async_copy16(Bs + li * 8, Bt + (size_t)(n0 + row) * K + k0 + cp * 8);
    }
    __syncthreads();
    bf16x8 af[4], bfr[4];
#pragma unroll
    for (int mi = 0; mi < 4; mi++)
      af[mi] = *(const bf16x8*)(As + (wr + mi * 16 + r) * BK + q * 8);
#pragma unroll
    for (int ni = 0; ni < 4; ni++)
      bfr[ni] = *(const bf16x8*)(Bs + (wc + ni * 16 + r) * BK + q * 8);
#pragma unroll
    for (int mi = 0; mi < 4; mi++)
#pragma unroll
      for (int ni = 0; ni < 4; ni++)
        acc[mi][ni] = __builtin_amdgcn_mfma_f32_16x16x32_bf16(af[mi], bfr[ni],
                                                              acc[mi][ni], 0, 0, 0);
    __syncthreads();
  }

  // epilogue: C layout col = lane&15, row = (lane>>4)*4 + reg
#pragma unroll
  for (int mi = 0; mi < 4; mi++) {
#pragma unroll
    for (int ni = 0; ni < 4; ni++) {
      int col = n0 + wc + ni * 16 + r;
      float bv = bias[col];
#pragma unroll
      for (int rg = 0; rg < 4; rg++) {
        int row = m0 + wr + mi * 16 + q * 4 + rg;
        size_t oidx = (size_t)row * N + col;
        float v = acc[mi][ni][rg] + bv;
        if constexpr (MODE == 2) v += resid[oidx];
        if constexpr (MODE == 1) {
          v = 0.5f * v * (1.0f + erff(v * 0.70710678118654752f));
          outb[oidx] = __float2bfloat16(v);
        } else {
          outf[oidx] = v;
        }
      }
    }
  }
}

// ---------------- final classifier ----------------
__global__ void classifier_k(const float* __restrict__ x,
                             const float* __restrict__ Wfc,
                             const float* __restrict__ bfc,
                             float* __restrict__ out) {
  int b = blockIdx.x, tid = threadIdx.x;
  const float* xb = x + (size_t)b * (SS * DD);
  float a0 = 0.f, a1 = 0.f;
  for (int i = tid; i < SS * DD; i += 256) {
    float xv = xb[i];
    a0 += xv * Wfc[2 * i];
    a1 += xv * Wfc[2 * i + 1];
  }
  __shared__ float sbuf[4];
  a0 = block_sum256(a0, sbuf);
  a1 = block_sum256(a1, sbuf);
  if (tid == 0) {
    out[2 * b] = a0 + bfc[0];
    out[2 * b + 1] = a1 + bfc[1];
  }
}

// ---------------- launcher ----------------
extern "C" void kernel_launch(void* const* d_in, const int* in_sizes, int n_in,
                              void* d_out, int out_size, void* d_ws, size_t ws_size,
                              hipStream_t stream) {
  const float* Tmpl = (const float*)d_in[0];
  const float* Pseq = (const float*)d_in[1];
  const float* Wc   = (const float*)d_in[2];
  const float* bc   = (const float*)d_in[3];
  const float* gp   = (const float*)d_in[4];
  const float* bp   = (const float*)d_in[5];
  const float* W1   = (const float*)d_in[6];
  const float* b1   = (const float*)d_in[7];
  const float* W2   = (const float*)d_in[8];
  const float* b2   = (const float*)d_in[9];
  const float* g1   = (const float*)d_in[10];
  const float* bn1  = (const float*)d_in[11];
  const float* g2   = (const float*)d_in[12];
  const float* bn2  = (const float*)d_in[13];
  const float* Wfc  = (const float*)d_in[14];
  const float* bfc  = (const float*)d_in[15];
  float* out = (float*)d_out;
  (void)in_sizes; (void)n_in; (void)out_size; (void)ws_size;

  char* ws = (char*)d_ws;
  size_t off = 0;
  auto alloc = [&](size_t n) { size_t o = off; off += (n + 255) & ~(size_t)255; return o; };

  __hip_bfloat16* Wct = (__hip_bfloat16*)(ws + alloc((size_t)768 * 768 * 2));
  __hip_bfloat16* W1t = (__hip_bfloat16*)(ws + alloc((size_t)768 * 3072 * 2));
  __hip_bfloat16* W2t = (__hip_bfloat16*)(ws + alloc((size_t)3072 * 768 * 2));
  size_t h1_off = alloc((size_t)ROWS * FF_ * 2);
  __hip_bfloat16* h1 = (__hip_bfloat16*)(ws + h1_off);
  float* param_enc = (float*)(ws + h1_off);            // alias: dead before h1 live
  size_t slb_off = alloc((size_t)ROWS * DD * 2);
  __hip_bfloat16* src_ln_bf = (__hip_bfloat16*)(ws + slb_off);
  __hip_bfloat16* pooled = (__hip_bfloat16*)(ws + slb_off);  // alias
  size_t ao_off = alloc((size_t)ROWS * DD * 4);
  float* attn_out_b = (float*)(ws + ao_off);
  float* pe_lin = (float*)(ws + ao_off);               // alias
  float* pbias = (float*)(ws + alloc((size_t)512 * SS * SS * 4));
  float* src = (float*)(ws + alloc((size_t)ROWS * DD * 4));
  float* src_ln = (float*)(ws + alloc((size_t)ROWS * DD * 4));
  float* z = (float*)(ws + alloc((size_t)ROWS * DD * 4));

  // ---- layer-invariant precompute ----
  convert_transpose<<<dim3(768 / 32, 768 / 32), 256, 0, stream>>>(Wc, Wct, 768, 768);
  convert_transpose<<<dim3(3072 / 32, 768 / 32), 256, 0, stream>>>(W1, W1t, 768, 3072);
  convert_transpose<<<dim3(768 / 32, 3072 / 32), 256, 0, stream>>>(W2, W2t, 3072, 768);
  pool_mean<<<ROWS * DD / 256, 256, 0, stream>>>(Pseq, pooled);
  gemm_bt<0><<<dim3(DD / 128, ROWS / 128), 256, 0, stream>>>(
      pooled, Wct, bc, nullptr, pe_lin, nullptr, ROWS, DD, 768);
  ln_row<false, false><<<ROWS, 256, 0, stream>>>(pe_lin, nullptr, gp, bp, param_enc, nullptr);
  param_bias_k<<<512, 256, 0, stream>>>(param_enc, pbias);
  add_pe<<<ROWS * DD / 256, 256, 0, stream>>>(Tmpl, src);

  // ---- 4 shared layers ----
  for (int l = 0; l < 4; ++l) {
    attn_fused_mfma<<<512, 256, 0, stream>>>(src, pbias, attn_out_b);
    ln_row<true, true><<<ROWS, 256, 0, stream>>>(attn_out_b, src, g1, bn1, src_ln, src_ln_bf);
    gemm_bt<1><<<dim3(FF_ / 128, ROWS / 128), 256, 0, stream>>>(
        src_ln_bf, W1t, b1, nullptr, nullptr, h1, ROWS, FF_, DD);
    gemm_bt<2><<<dim3(DD / 128, ROWS / 128), 256, 0, stream>>>(
        h1, W2t, b2, src_ln, z, nullptr, ROWS, DD, FF_);
    ln_row<false, false><<<ROWS, 256, 0, stream>>>(z, nullptr, g2, bn2, src, nullptr);
  }

  classifier_k<<<BB, 256, 0, stream>>>(src, Wfc, bfc, out);
}

// Round 4
// 1087.818 us; speedup vs baseline: 1.8820x; 1.1056x over previous
//
#include <hip/hip_runtime.h>
#include <hip/hip_bf16.h>
#include <math.h>

// Model: B=64,S=100,D=768,H=8,P=8,FF=3072,HD=96, 4 shared layers.
//  - param path computed ONCE (layer-shared).
//  - big GEMMs: bf16 MFMA 128x128 tile + global_load_lds width-16 staging (R2).
//  - attention per (b,h): MFMA scores (pbias C-init) + reg-softmax + MFMA PV (R2).
//  - split-K classifier (1600 blocks) + float4-vectorized LayerNorm (R3).

typedef __attribute__((ext_vector_type(8))) short bf16x8;
typedef __attribute__((ext_vector_type(4))) float f32x4;
typedef __attribute__((ext_vector_type(4))) short short4v;

#define BB 64
#define SS 100
#define DD 768
#define HH 8
#define HD 96
#define FF_ 3072
#define ROWS 6400           // B*S
#define LN10000 9.210340371976184f

__device__ __forceinline__ void async_copy16(void* lds_dst, const void* gsrc) {
  __builtin_amdgcn_global_load_lds(
      (const __attribute__((address_space(1))) void*)gsrc,
      (__attribute__((address_space(3))) void*)lds_dst, 16, 0, 0);
}

// ---------------- block-wide sums ----------------
__device__ __forceinline__ float block_sum256(float v, float* sbuf) {
#pragma unroll
  for (int o = 32; o > 0; o >>= 1) v += __shfl_xor(v, o, 64);
  int tid = threadIdx.x;
  __syncthreads();
  if ((tid & 63) == 0) sbuf[tid >> 6] = v;
  __syncthreads();
  return sbuf[0] + sbuf[1] + sbuf[2] + sbuf[3];
}

__device__ __forceinline__ float block_sum192(float v, float* sbuf) {
#pragma unroll
  for (int o = 32; o > 0; o >>= 1) v += __shfl_xor(v, o, 64);
  int tid = threadIdx.x;
  __syncthreads();
  if ((tid & 63) == 0) sbuf[tid >> 6] = v;
  __syncthreads();
  return sbuf[0] + sbuf[1] + sbuf[2];
}

// ---------------- fp32 [K,N] -> bf16 [N,K] transpose-convert ----------------
__global__ void convert_transpose(const float* __restrict__ in,
                                  __hip_bfloat16* __restrict__ out,
                                  int K, int N) {
  __shared__ float t[32][33];
  int n0 = blockIdx.x * 32, k0 = blockIdx.y * 32;
  int tid = threadIdx.x;
  int tx = tid & 31, ty = tid >> 5;  // ty 0..7
#pragma unroll
  for (int j = 0; j < 32; j += 8)
    t[ty + j][tx] = in[(size_t)(k0 + ty + j) * N + n0 + tx];
  __syncthreads();
#pragma unroll
  for (int j = 0; j < 32; j += 8)
    out[(size_t)(n0 + ty + j) * K + k0 + tx] = __float2bfloat16(t[tx][ty + j]);
}

// ---------------- pooled = mean_P(param_seq) -> bf16 ----------------
__global__ void pool_mean(const float* __restrict__ ps,
                          __hip_bfloat16* __restrict__ pooled) {
  int idx = blockIdx.x * 256 + threadIdx.x;  // < 6400*768
  int row = idx / DD, c = idx - row * DD;
  float s = 0.f;
#pragma unroll
  for (int p = 0; p < 8; p++) s += ps[(size_t)(row * 8 + p) * DD + c];
  pooled[idx] = __float2bfloat16(s * 0.125f);
}

// ---------------- src = template + PE ----------------
__global__ void add_pe(const float* __restrict__ t, float* __restrict__ src) {
  int idx = blockIdx.x * 256 + threadIdx.x;
  int row = idx / DD, c = idx - row * DD;
  int srow = row % SS;
  int c2 = c & ~1;
  float ang = (float)srow * expf((float)c2 * (-LN10000 / (float)DD));
  float pe = (c & 1) ? cosf(ang) : sinf(ang);
  src[idx] = t[idx] + pe;
}

// ---------------- LayerNorm over rows of 768 (192 thr, float4) ----------------
template <bool RESID, bool WB16>
__global__ void ln_row(const float* __restrict__ X, const float* __restrict__ R,
                       const float* __restrict__ g, const float* __restrict__ bb,
                       float* __restrict__ of, __hip_bfloat16* __restrict__ ob) {
  int row = blockIdx.x, tid = threadIdx.x;
  size_t base = (size_t)row * DD;
  int c4 = tid * 4;
  float4 v = *(const float4*)(X + base + c4);
  if (RESID) {
    float4 rv = *(const float4*)(R + base + c4);
    v.x += rv.x; v.y += rv.y; v.z += rv.z; v.w += rv.w;
  }
  __shared__ float sbuf[3];
  float s = block_sum192(v.x + v.y + v.z + v.w, sbuf);
  float mean = s * (1.0f / DD);
  float dx = v.x - mean, dy = v.y - mean, dz = v.z - mean, dw = v.w - mean;
  float ss = block_sum192(dx * dx + dy * dy + dz * dz + dw * dw, sbuf);
  float rs = rsqrtf(ss * (1.0f / DD) + 1e-5f);
  float4 gv = *(const float4*)(g + c4);
  float4 bv = *(const float4*)(bb + c4);
  float4 y;
  y.x = dx * rs * gv.x + bv.x;
  y.y = dy * rs * gv.y + bv.y;
  y.z = dz * rs * gv.z + bv.z;
  y.w = dw * rs * gv.w + bv.w;
  *(float4*)(of + base + c4) = y;
  if (WB16) {
    __hip_bfloat16 hb[4] = {__float2bfloat16(y.x), __float2bfloat16(y.y),
                            __float2bfloat16(y.z), __float2bfloat16(y.w)};
    *(short4v*)(ob + base + c4) = *(short4v*)hb;
  }
}

// ---------------- param_bias[b,h,q,k] = pb.pb^T / sqrt(HD) ----------------
__global__ void param_bias_k(const float* __restrict__ penc,
                             float* __restrict__ pbias) {
  int bh = blockIdx.x;
  int b = bh >> 3, h = bh & 7;
  __shared__ float ps[SS][HD + 1];
  int tid = threadIdx.x;
  for (int i = tid; i < SS * HD; i += 256) {
    int s = i / HD, d = i - s * HD;
    ps[s][d] = penc[(size_t)(b * SS + s) * DD + h * HD + d];
  }
  __syncthreads();
  const float scale = 0.1020620726159658f;  // 1/sqrt(96)
  float* pb = pbias + (size_t)bh * SS * SS;
  for (int i = tid; i < SS * SS; i += 256) {
    int q = i / SS, k = i - q * SS;
    float acc = 0.f;
#pragma unroll 4
    for (int d = 0; d < HD; d++) acc += ps[q][d] * ps[k][d];
    pb[i] = acc * scale;
  }
}

// ---------------- fused MFMA attention per (b,h) ----------------
__launch_bounds__(256, 2)
__global__ void attn_fused_mfma(const float* __restrict__ src,
                                const float* __restrict__ pbias,
                                float* __restrict__ out) {
  __shared__ __align__(16) char umem[128 * 136 * 2];  // Qs[128][104] then Ps[128][136]
  __shared__ __align__(16) __hip_bfloat16 Qt[96][136];
  __shared__ float redm[2][128];
  __shared__ float reds[2][128];
  __hip_bfloat16 (*Qs)[104] = (__hip_bfloat16 (*)[104])umem;
  __hip_bfloat16 (*Ps)[136] = (__hip_bfloat16 (*)[136])umem;

  const int bh = blockIdx.x;
  const int b = bh >> 3, h = bh & 7;
  const int tid = threadIdx.x;
  const int wave = tid >> 6, lane = tid & 63;
  const int r = lane & 15, quad = lane >> 4;
  const int q8 = quad * 8;
  const int wr = (wave >> 1) * 64, wc = (wave & 1) * 64;

  const float sroot = rsqrtf(9.79795897113f);  // 96^(-1/4)
  for (int i = tid; i < SS * HD; i += 256) {
    int s = i / HD, d = i - s * HD;
    float v = src[(size_t)(b * SS + s) * DD + h * HD + d];
    Qs[s][d] = __float2bfloat16(v * sroot);
    Qt[d][s] = __float2bfloat16(v);
  }
  for (int i = tid; i < 28 * HD; i += 256) {  // zero pads
    int s = i / HD, d = i - s * HD;           // s in 0..27
    Qs[100 + s][d] = __float2bfloat16(0.f);
    Qt[d][100 + s] = __float2bfloat16(0.f);
  }

  const float* pb = pbias + (size_t)bh * SS * SS;
  bool cv[4]; int cols[4];
#pragma unroll
  for (int ni = 0; ni < 4; ni++) { cols[ni] = wc + ni * 16 + r; cv[ni] = cols[ni] < SS; }
  f32x4 acc[4][4];
#pragma unroll
  for (int mi = 0; mi < 4; mi++)
#pragma unroll
    for (int rg = 0; rg < 4; rg++) {
      int row = wr + mi * 16 + quad * 4 + rg;
#pragma unroll
      for (int ni = 0; ni < 4; ni++)
        acc[mi][ni][rg] = (row < SS && cv[ni]) ? pb[row * SS + cols[ni]] : 0.f;
    }
  __syncthreads();

#pragma unroll
  for (int k0 = 0; k0 < HD; k0 += 32) {
    bf16x8 af[4], bfv[4];
#pragma unroll
    for (int mi = 0; mi < 4; mi++)
      af[mi] = *(const bf16x8*)&Qs[wr + mi * 16 + r][k0 + q8];
#pragma unroll
    for (int ni = 0; ni < 4; ni++)
      bfv[ni] = *(const bf16x8*)&Qs[wc + ni * 16 + r][k0 + q8];
#pragma unroll
    for (int mi = 0; mi < 4; mi++)
#pragma unroll
      for (int ni = 0; ni < 4; ni++)
        acc[mi][ni] = __builtin_amdgcn_mfma_f32_16x16x32_bf16(af[mi], bfv[ni],
                                                              acc[mi][ni], 0, 0, 0);
  }

  float mx[4][4];
#pragma unroll
  for (int mi = 0; mi < 4; mi++)
#pragma unroll
    for (int rg = 0; rg < 4; rg++) {
      float m = -1e30f;
#pragma unroll
      for (int ni = 0; ni < 4; ni++)
        if (cv[ni]) m = fmaxf(m, acc[mi][ni][rg]);
#pragma unroll
      for (int o = 1; o < 16; o <<= 1) m = fmaxf(m, __shfl_xor(m, o, 64));
      mx[mi][rg] = m;
    }
  if (r == 0) {
#pragma unroll
    for (int mi = 0; mi < 4; mi++)
#pragma unroll
      for (int rg = 0; rg < 4; rg++)
        redm[wave & 1][wr + mi * 16 + quad * 4 + rg] = mx[mi][rg];
  }
  __syncthreads();

#pragma unroll
  for (int mi = 0; mi < 4; mi++)
#pragma unroll
    for (int rg = 0; rg < 4; rg++) {
      int row = wr + mi * 16 + quad * 4 + rg;
      float rmax = fmaxf(redm[0][row], redm[1][row]);
      float s = 0.f;
#pragma unroll
      for (int ni = 0; ni < 4; ni++) {
        float e = cv[ni] ? __expf(acc[mi][ni][rg] - rmax) : 0.f;
        acc[mi][ni][rg] = e;
        s += e;
      }
#pragma unroll
      for (int o = 1; o < 16; o <<= 1) s += __shfl_xor(s, o, 64);
      if (r == 0) reds[wave & 1][row] = s;
    }
  __syncthreads();

#pragma unroll
  for (int mi = 0; mi < 4; mi++)
#pragma unroll
    for (int rg = 0; rg < 4; rg++) {
      int row = wr + mi * 16 + quad * 4 + rg;
      float inv = 1.0f / (reds[0][row] + reds[1][row]);
#pragma unroll
      for (int ni = 0; ni < 4; ni++)
        Ps[row][cols[ni]] = __float2bfloat16(acc[mi][ni][rg] * inv);
    }
  __syncthreads();

  const int wr2 = (wave >> 1) * 48;
  f32x4 po[3][4] = {};
#pragma unroll
  for (int kk = 0; kk < 128; kk += 32) {
    bf16x8 aq[3], bp[4];
#pragma unroll
    for (int mi = 0; mi < 3; mi++)
      aq[mi] = *(const bf16x8*)&Qt[wr2 + mi * 16 + r][kk + q8];
#pragma unroll
    for (int ni = 0; ni < 4; ni++)
      bp[ni] = *(const bf16x8*)&Ps[wc + ni * 16 + r][kk + q8];
#pragma unroll
    for (int mi = 0; mi < 3; mi++)
#pragma unroll
      for (int ni = 0; ni < 4; ni++)
        po[mi][ni] = __builtin_amdgcn_mfma_f32_16x16x32_bf16(aq[mi], bp[ni],
                                                             po[mi][ni], 0, 0, 0);
  }
#pragma unroll
  for (int mi = 0; mi < 3; mi++)
#pragma unroll
    for (int ni = 0; ni < 4; ni++) {
      int qcol = wc + ni * 16 + r;
      if (qcol < SS) {
#pragma unroll
        for (int rg = 0; rg < 4; rg++) {
          int d = wr2 + mi * 16 + quad * 4 + rg;
          out[(size_t)(b * SS + qcol) * DD + h * HD + d] = po[mi][ni][rg];
        }
      }
    }
}

// ---------------- bf16 MFMA GEMM: C[M,N] = A[M,K] @ Bt[N,K]^T ----------------
template <int MODE>
__launch_bounds__(256, 2)
__global__ void gemm_bt(const __hip_bfloat16* __restrict__ A,
                        const __hip_bfloat16* __restrict__ Bt,
                        const float* __restrict__ bias,
                        const float* __restrict__ resid,
                        float* __restrict__ outf,
                        __hip_bfloat16* __restrict__ outb,
                        int M, int N, int K) {
  constexpr int BM = 128, BN = 128, BK = 32;
  __shared__ __align__(16) __hip_bfloat16 As[BM * BK];
  __shared__ __align__(16) __hip_bfloat16 Bs[BN * BK];
  const int tid = threadIdx.x;
  const int wave = tid >> 6, lane = tid & 63;
  const int wr = (wave >> 1) * 64, wc = (wave & 1) * 64;
  const int m0 = blockIdx.y * BM, n0 = blockIdx.x * BN;
  const int r = lane & 15, q = lane >> 4;

  f32x4 acc[4][4] = {};

  for (int k0 = 0; k0 < K; k0 += BK) {
#pragma unroll
    for (int j = 0; j < 2; j++) {
      int li = tid + 256 * j;           // 0..511
      int row = li >> 2, cp = li & 3;   // 4 x 16B per 64B row
      async_copy16(As + li * 8, A + (size_t)(m0 + row) * K + k0 + cp * 8);
      async_copy16(Bs + li * 8, Bt + (size_t)(n0 + row) * K + k0 + cp * 8);
    }
    __syncthreads();
    bf16x8 af[4], bfr[4];
#pragma unroll
    for (int mi = 0; mi < 4; mi++)
      af[mi] = *(const bf16x8*)(As + (wr + mi * 16 + r) * BK + q * 8);
#pragma unroll
    for (int ni = 0; ni < 4; ni++)
      bfr[ni] = *(const bf16x8*)(Bs + (wc + ni * 16 + r) * BK + q * 8);
#pragma unroll
    for (int mi = 0; mi < 4; mi++)
#pragma unroll
      for (int ni = 0; ni < 4; ni++)
        acc[mi][ni] = __builtin_amdgcn_mfma_f32_16x16x32_bf16(af[mi], bfr[ni],
                                                              acc[mi][ni], 0, 0, 0);
    __syncthreads();
  }

#pragma unroll
  for (int mi = 0; mi < 4; mi++) {
#pragma unroll
    for (int ni = 0; ni < 4; ni++) {
      int col = n0 + wc + ni * 16 + r;
      float bv = bias[col];
#pragma unroll
      for (int rg = 0; rg < 4; rg++) {
        int row = m0 + wr + mi * 16 + q * 4 + rg;
        size_t oidx = (size_t)row * N + col;
        float v = acc[mi][ni][rg] + bv;
        if constexpr (MODE == 2) v += resid[oidx];
        if constexpr (MODE == 1) {
          v = 0.5f * v * (1.0f + erff(v * 0.70710678118654752f));
          outb[oidx] = __float2bfloat16(v);
        } else {
          outf[oidx] = v;
        }
      }
    }
  }
}

// ---------------- split-K classifier ----------------
#define CCHUNK 3072
#define NCHUNK 25   // 76800 / 3072
__global__ void classifier_part(const float* __restrict__ x,
                                const float* __restrict__ Wfc,
                                float* __restrict__ part) {
  int chunk = blockIdx.x, b = blockIdx.y, tid = threadIdx.x;
  const float* xb = x + (size_t)b * (SS * DD) + chunk * CCHUNK;
  const float* w = Wfc + 2 * (size_t)chunk * CCHUNK;
  float a0 = 0.f, a1 = 0.f;
  for (int i = tid; i < CCHUNK; i += 256) {
    float xv = xb[i];
    float2 wv = *(const float2*)(w + 2 * i);
    a0 += xv * wv.x;
    a1 += xv * wv.y;
  }
  __shared__ float sbuf[4];
  a0 = block_sum256(a0, sbuf);
  a1 = block_sum256(a1, sbuf);
  if (tid == 0) {
    part[(b * NCHUNK + chunk) * 2] = a0;
    part[(b * NCHUNK + chunk) * 2 + 1] = a1;
  }
}

__global__ void classifier_final(const float* __restrict__ part,
                                 const float* __restrict__ bfc,
                                 float* __restrict__ out) {
  int b = threadIdx.x;  // 64 threads
  float a0 = bfc[0], a1 = bfc[1];
#pragma unroll
  for (int c = 0; c < NCHUNK; c++) {
    a0 += part[(b * NCHUNK + c) * 2];
    a1 += part[(b * NCHUNK + c) * 2 + 1];
  }
  out[2 * b] = a0;
  out[2 * b + 1] = a1;
}

// ---------------- launcher ----------------
extern "C" void kernel_launch(void* const* d_in, const int* in_sizes, int n_in,
                              void* d_out, int out_size, void* d_ws, size_t ws_size,
                              hipStream_t stream) {
  const float* Tmpl = (const float*)d_in[0];
  const float* Pseq = (const float*)d_in[1];
  const float* Wc   = (const float*)d_in[2];
  const float* bc   = (const float*)d_in[3];
  const float* gp   = (const float*)d_in[4];
  const float* bp   = (const float*)d_in[5];
  const float* W1   = (const float*)d_in[6];
  const float* b1   = (const float*)d_in[7];
  const float* W2   = (const float*)d_in[8];
  const float* b2   = (const float*)d_in[9];
  const float* g1   = (const float*)d_in[10];
  const float* bn1  = (const float*)d_in[11];
  const float* g2   = (const float*)d_in[12];
  const float* bn2  = (const float*)d_in[13];
  const float* Wfc  = (const float*)d_in[14];
  const float* bfc  = (const float*)d_in[15];
  float* out = (float*)d_out;
  (void)in_sizes; (void)n_in; (void)out_size; (void)ws_size;

  char* ws = (char*)d_ws;
  size_t off = 0;
  auto alloc = [&](size_t n) { size_t o = off; off += (n + 255) & ~(size_t)255; return o; };

  __hip_bfloat16* Wct = (__hip_bfloat16*)(ws + alloc((size_t)768 * 768 * 2));
  __hip_bfloat16* W1t = (__hip_bfloat16*)(ws + alloc((size_t)768 * 3072 * 2));
  __hip_bfloat16* W2t = (__hip_bfloat16*)(ws + alloc((size_t)3072 * 768 * 2));
  size_t h1_off = alloc((size_t)ROWS * FF_ * 2);
  __hip_bfloat16* h1 = (__hip_bfloat16*)(ws + h1_off);
  float* param_enc = (float*)(ws + h1_off);            // alias: dead before h1 live
  size_t slb_off = alloc((size_t)ROWS * DD * 2);
  __hip_bfloat16* src_ln_bf = (__hip_bfloat16*)(ws + slb_off);
  __hip_bfloat16* pooled = (__hip_bfloat16*)(ws + slb_off);  // alias
  size_t ao_off = alloc((size_t)ROWS * DD * 4);
  float* attn_out_b = (float*)(ws + ao_off);
  float* pe_lin = (float*)(ws + ao_off);               // alias
  float* pbias = (float*)(ws + alloc((size_t)512 * SS * SS * 4));
  float* src = (float*)(ws + alloc((size_t)ROWS * DD * 4));
  float* src_ln = (float*)(ws + alloc((size_t)ROWS * DD * 4));
  float* z = (float*)(ws + alloc((size_t)ROWS * DD * 4));
  float* cpart = (float*)(ws + alloc((size_t)BB * NCHUNK * 2 * 4));

  // ---- layer-invariant precompute ----
  convert_transpose<<<dim3(768 / 32, 768 / 32), 256, 0, stream>>>(Wc, Wct, 768, 768);
  convert_transpose<<<dim3(3072 / 32, 768 / 32), 256, 0, stream>>>(W1, W1t, 768, 3072);
  convert_transpose<<<dim3(768 / 32, 3072 / 32), 256, 0, stream>>>(W2, W2t, 3072, 768);
  pool_mean<<<ROWS * DD / 256, 256, 0, stream>>>(Pseq, pooled);
  gemm_bt<0><<<dim3(DD / 128, ROWS / 128), 256, 0, stream>>>(
      pooled, Wct, bc, nullptr, pe_lin, nullptr, ROWS, DD, 768);
  ln_row<false, false><<<ROWS, 192, 0, stream>>>(pe_lin, nullptr, gp, bp, param_enc, nullptr);
  param_bias_k<<<512, 256, 0, stream>>>(param_enc, pbias);
  add_pe<<<ROWS * DD / 256, 256, 0, stream>>>(Tmpl, src);

  // ---- 4 shared layers ----
  for (int l = 0; l < 4; ++l) {
    attn_fused_mfma<<<512, 256, 0, stream>>>(src, pbias, attn_out_b);
    ln_row<true, true><<<ROWS, 192, 0, stream>>>(attn_out_b, src, g1, bn1, src_ln, src_ln_bf);
    gemm_bt<1><<<dim3(FF_ / 128, ROWS / 128), 256, 0, stream>>>(
        src_ln_bf, W1t, b1, nullptr, nullptr, h1, ROWS, FF_, DD);
    gemm_bt<2><<<dim3(DD / 128, ROWS / 128), 256, 0, stream>>>(
        h1, W2t, b2, src_ln, z, nullptr, ROWS, DD, FF_);
    ln_row<false, false><<<ROWS, 192, 0, stream>>>(z, nullptr, g2, bn2, src, nullptr);
  }

  classifier_part<<<dim3(NCHUNK, BB), 256, 0, stream>>>(src, Wfc, cpart);
  classifier_final<<<1, 64, 0, stream>>>(cpart, bfc, out);
}

// Round 5
// 1075.944 us; speedup vs baseline: 1.9028x; 1.0110x over previous
//
#include <hip/hip_runtime.h>
#include <hip/hip_bf16.h>
#include <math.h>

// Model: B=64,S=100,D=768,H=8,P=8,FF=3072,HD=96, 4 shared layers.
//  - param path computed ONCE (layer-shared); param_bias via MFMA (R4).
//  - big GEMMs: bf16 MFMA 128x128 tile + global_load_lds width-16 staging,
//    no min-wave clamp (let allocator hit ~3 blocks/CU like m97) (R4).
//  - attention per (b,h): MFMA scores (pbias C-init) + reg-softmax + MFMA PV,
//    bf16 packed output (R4).
//  - split-K classifier + float4-vectorized LayerNorm.

typedef __attribute__((ext_vector_type(8))) short bf16x8;
typedef __attribute__((ext_vector_type(4))) float f32x4;
typedef __attribute__((ext_vector_type(4))) short short4v;

#define BB 64
#define SS 100
#define DD 768
#define HH 8
#define HD 96
#define FF_ 3072
#define ROWS 6400           // B*S
#define LN10000 9.210340371976184f

__device__ __forceinline__ void async_copy16(void* lds_dst, const void* gsrc) {
  __builtin_amdgcn_global_load_lds(
      (const __attribute__((address_space(1))) void*)gsrc,
      (__attribute__((address_space(3))) void*)lds_dst, 16, 0, 0);
}

// ---------------- block-wide sums ----------------
__device__ __forceinline__ float block_sum256(float v, float* sbuf) {
#pragma unroll
  for (int o = 32; o > 0; o >>= 1) v += __shfl_xor(v, o, 64);
  int tid = threadIdx.x;
  __syncthreads();
  if ((tid & 63) == 0) sbuf[tid >> 6] = v;
  __syncthreads();
  return sbuf[0] + sbuf[1] + sbuf[2] + sbuf[3];
}

__device__ __forceinline__ float block_sum192(float v, float* sbuf) {
#pragma unroll
  for (int o = 32; o > 0; o >>= 1) v += __shfl_xor(v, o, 64);
  int tid = threadIdx.x;
  __syncthreads();
  if ((tid & 63) == 0) sbuf[tid >> 6] = v;
  __syncthreads();
  return sbuf[0] + sbuf[1] + sbuf[2];
}

// ---------------- fp32 [K,N] -> bf16 [N,K] transpose-convert ----------------
__global__ void convert_transpose(const float* __restrict__ in,
                                  __hip_bfloat16* __restrict__ out,
                                  int K, int N) {
  __shared__ float t[32][33];
  int n0 = blockIdx.x * 32, k0 = blockIdx.y * 32;
  int tid = threadIdx.x;
  int tx = tid & 31, ty = tid >> 5;  // ty 0..7
#pragma unroll
  for (int j = 0; j < 32; j += 8)
    t[ty + j][tx] = in[(size_t)(k0 + ty + j) * N + n0 + tx];
  __syncthreads();
#pragma unroll
  for (int j = 0; j < 32; j += 8)
    out[(size_t)(n0 + ty + j) * K + k0 + tx] = __float2bfloat16(t[tx][ty + j]);
}

// ---------------- pooled = mean_P(param_seq) -> bf16 ----------------
__global__ void pool_mean(const float* __restrict__ ps,
                          __hip_bfloat16* __restrict__ pooled) {
  int idx = blockIdx.x * 256 + threadIdx.x;  // < 6400*768
  int row = idx / DD, c = idx - row * DD;
  float s = 0.f;
#pragma unroll
  for (int p = 0; p < 8; p++) s += ps[(size_t)(row * 8 + p) * DD + c];
  pooled[idx] = __float2bfloat16(s * 0.125f);
}

// ---------------- src = template + PE ----------------
__global__ void add_pe(const float* __restrict__ t, float* __restrict__ src) {
  int idx = blockIdx.x * 256 + threadIdx.x;
  int row = idx / DD, c = idx - row * DD;
  int srow = row % SS;
  int c2 = c & ~1;
  float ang = (float)srow * expf((float)c2 * (-LN10000 / (float)DD));
  float pe = (c & 1) ? cosf(ang) : sinf(ang);
  src[idx] = t[idx] + pe;
}

// ---------------- LayerNorm over rows of 768 (192 thr, float4) ----------------
// XB16: X is bf16; RESID: add R (fp32); WB16: also write bf16 copy
template <bool XB16, bool RESID, bool WB16>
__global__ void ln_row(const float* __restrict__ Xf,
                       const __hip_bfloat16* __restrict__ Xb,
                       const float* __restrict__ R,
                       const float* __restrict__ g, const float* __restrict__ bb,
                       float* __restrict__ of, __hip_bfloat16* __restrict__ ob) {
  int row = blockIdx.x, tid = threadIdx.x;
  size_t base = (size_t)row * DD;
  int c4 = tid * 4;
  float4 v;
  if constexpr (XB16) {
    short4v xv = *(const short4v*)(Xb + base + c4);
    __hip_bfloat16* p = (__hip_bfloat16*)&xv;
    v.x = __bfloat162float(p[0]); v.y = __bfloat162float(p[1]);
    v.z = __bfloat162float(p[2]); v.w = __bfloat162float(p[3]);
  } else {
    v = *(const float4*)(Xf + base + c4);
  }
  if (RESID) {
    float4 rv = *(const float4*)(R + base + c4);
    v.x += rv.x; v.y += rv.y; v.z += rv.z; v.w += rv.w;
  }
  __shared__ float sbuf[3];
  float s = block_sum192(v.x + v.y + v.z + v.w, sbuf);
  float mean = s * (1.0f / DD);
  float dx = v.x - mean, dy = v.y - mean, dz = v.z - mean, dw = v.w - mean;
  float ss = block_sum192(dx * dx + dy * dy + dz * dz + dw * dw, sbuf);
  float rs = rsqrtf(ss * (1.0f / DD) + 1e-5f);
  float4 gv = *(const float4*)(g + c4);
  float4 bv = *(const float4*)(bb + c4);
  float4 y;
  y.x = dx * rs * gv.x + bv.x;
  y.y = dy * rs * gv.y + bv.y;
  y.z = dz * rs * gv.z + bv.z;
  y.w = dw * rs * gv.w + bv.w;
  *(float4*)(of + base + c4) = y;
  if (WB16) {
    __hip_bfloat16 hb[4] = {__float2bfloat16(y.x), __float2bfloat16(y.y),
                            __float2bfloat16(y.z), __float2bfloat16(y.w)};
    *(short4v*)(ob + base + c4) = *(short4v*)hb;
  }
}

// ---------------- param_bias via MFMA: pb.pb^T / sqrt(HD) ----------------
__launch_bounds__(256, 2)
__global__ void param_bias_mfma(const float* __restrict__ penc,
                                float* __restrict__ pbias) {
  __shared__ __align__(16) __hip_bfloat16 Qs[128][104];
  const int bh = blockIdx.x;
  const int b = bh >> 3, h = bh & 7;
  const int tid = threadIdx.x;
  const int wave = tid >> 6, lane = tid & 63;
  const int r = lane & 15, quad = lane >> 4;
  const int q8 = quad * 8;
  const int wr = (wave >> 1) * 64, wc = (wave & 1) * 64;
  const float sroot = rsqrtf(9.79795897113f);  // 96^(-1/4)
  for (int i = tid; i < 128 * HD; i += 256) {
    int s = i / HD, d = i - s * HD;
    float v = (s < SS) ? penc[(size_t)(b * SS + s) * DD + h * HD + d] : 0.f;
    Qs[s][d] = __float2bfloat16(v * sroot);
  }
  __syncthreads();
  f32x4 acc[4][4] = {};
#pragma unroll
  for (int k0 = 0; k0 < HD; k0 += 32) {
    bf16x8 af[4], bfv[4];
#pragma unroll
    for (int mi = 0; mi < 4; mi++)
      af[mi] = *(const bf16x8*)&Qs[wr + mi * 16 + r][k0 + q8];
#pragma unroll
    for (int ni = 0; ni < 4; ni++)
      bfv[ni] = *(const bf16x8*)&Qs[wc + ni * 16 + r][k0 + q8];
#pragma unroll
    for (int mi = 0; mi < 4; mi++)
#pragma unroll
      for (int ni = 0; ni < 4; ni++)
        acc[mi][ni] = __builtin_amdgcn_mfma_f32_16x16x32_bf16(af[mi], bfv[ni],
                                                              acc[mi][ni], 0, 0, 0);
  }
  float* pb = pbias + (size_t)bh * SS * SS;
#pragma unroll
  for (int mi = 0; mi < 4; mi++)
#pragma unroll
    for (int ni = 0; ni < 4; ni++) {
      int col = wc + ni * 16 + r;
      if (col < SS) {
#pragma unroll
        for (int rg = 0; rg < 4; rg++) {
          int row = wr + mi * 16 + quad * 4 + rg;
          if (row < SS) pb[row * SS + col] = acc[mi][ni][rg];
        }
      }
    }
}

// ---------------- fused MFMA attention per (b,h) ----------------
__launch_bounds__(256, 2)
__global__ void attn_fused_mfma(const float* __restrict__ src,
                                const float* __restrict__ pbias,
                                __hip_bfloat16* __restrict__ out) {
  __shared__ __align__(16) char umem[128 * 136 * 2];  // Qs[128][104] then Ps[128][136]
  __shared__ __align__(16) __hip_bfloat16 Qt[96][136];
  __shared__ float redm[2][128];
  __shared__ float reds[2][128];
  __hip_bfloat16 (*Qs)[104] = (__hip_bfloat16 (*)[104])umem;
  __hip_bfloat16 (*Ps)[136] = (__hip_bfloat16 (*)[136])umem;

  const int bh = blockIdx.x;
  const int b = bh >> 3, h = bh & 7;
  const int tid = threadIdx.x;
  const int wave = tid >> 6, lane = tid & 63;
  const int r = lane & 15, quad = lane >> 4;
  const int q8 = quad * 8;
  const int wr = (wave >> 1) * 64, wc = (wave & 1) * 64;

  const float sroot = rsqrtf(9.79795897113f);  // 96^(-1/4)
  for (int i = tid; i < SS * HD; i += 256) {
    int s = i / HD, d = i - s * HD;
    float v = src[(size_t)(b * SS + s) * DD + h * HD + d];
    Qs[s][d] = __float2bfloat16(v * sroot);
    Qt[d][s] = __float2bfloat16(v);
  }
  for (int i = tid; i < 28 * HD; i += 256) {  // zero pads
    int s = i / HD, d = i - s * HD;           // s in 0..27
    Qs[100 + s][d] = __float2bfloat16(0.f);
    Qt[d][100 + s] = __float2bfloat16(0.f);
  }

  const float* pb = pbias + (size_t)bh * SS * SS;
  bool cv[4]; int cols[4];
#pragma unroll
  for (int ni = 0; ni < 4; ni++) { cols[ni] = wc + ni * 16 + r; cv[ni] = cols[ni] < SS; }
  f32x4 acc[4][4];
#pragma unroll
  for (int mi = 0; mi < 4; mi++)
#pragma unroll
    for (int rg = 0; rg < 4; rg++) {
      int row = wr + mi * 16 + quad * 4 + rg;
#pragma unroll
      for (int ni = 0; ni < 4; ni++)
        acc[mi][ni][rg] = (row < SS && cv[ni]) ? pb[row * SS + cols[ni]] : 0.f;
    }
  __syncthreads();

#pragma unroll
  for (int k0 = 0; k0 < HD; k0 += 32) {
    bf16x8 af[4], bfv[4];
#pragma unroll
    for (int mi = 0; mi < 4; mi++)
      af[mi] = *(const bf16x8*)&Qs[wr + mi * 16 + r][k0 + q8];
#pragma unroll
    for (int ni = 0; ni < 4; ni++)
      bfv[ni] = *(const bf16x8*)&Qs[wc + ni * 16 + r][k0 + q8];
#pragma unroll
    for (int mi = 0; mi < 4; mi++)
#pragma unroll
      for (int ni = 0; ni < 4; ni++)
        acc[mi][ni] = __builtin_amdgcn_mfma_f32_16x16x32_bf16(af[mi], bfv[ni],
                                                              acc[mi][ni], 0, 0, 0);
  }

  float mx[4][4];
#pragma unroll
  for (int mi = 0; mi < 4; mi++)
#pragma unroll
    for (int rg = 0; rg < 4; rg++) {
      float m = -1e30f;
#pragma unroll
      for (int ni = 0; ni < 4; ni++)
        if (cv[ni]) m = fmaxf(m, acc[mi][ni][rg]);
#pragma unroll
      for (int o = 1; o < 16; o <<= 1) m = fmaxf(m, __shfl_xor(m, o, 64));
      mx[mi][rg] = m;
    }
  if (r == 0) {
#pragma unroll
    for (int mi = 0; mi < 4; mi++)
#pragma unroll
      for (int rg = 0; rg < 4; rg++)
        redm[wave & 1][wr + mi * 16 + quad * 4 + rg] = mx[mi][rg];
  }
  __syncthreads();

#pragma unroll
  for (int mi = 0; mi < 4; mi++)
#pragma unroll
    for (int rg = 0; rg < 4; rg++) {
      int row = wr + mi * 16 + quad * 4 + rg;
      float rmax = fmaxf(redm[0][row], redm[1][row]);
      float s = 0.f;
#pragma unroll
      for (int ni = 0; ni < 4; ni++) {
        float e = cv[ni] ? __expf(acc[mi][ni][rg] - rmax) : 0.f;
        acc[mi][ni][rg] = e;
        s += e;
      }
#pragma unroll
      for (int o = 1; o < 16; o <<= 1) s += __shfl_xor(s, o, 64);
      if (r == 0) reds[wave & 1][row] = s;
    }
  __syncthreads();

#pragma unroll
  for (int mi = 0; mi < 4; mi++)
#pragma unroll
    for (int rg = 0; rg < 4; rg++) {
      int row = wr + mi * 16 + quad * 4 + rg;
      float inv = 1.0f / (reds[0][row] + reds[1][row]);
#pragma unroll
      for (int ni = 0; ni < 4; ni++)
        Ps[row][cols[ni]] = __float2bfloat16(acc[mi][ni][rg] * inv);
    }
  __syncthreads();

  const int wr2 = (wave >> 1) * 48;
  f32x4 po[3][4] = {};
#pragma unroll
  for (int kk = 0; kk < 128; kk += 32) {
    bf16x8 aq[3], bp[4];
#pragma unroll
    for (int mi = 0; mi < 3; mi++)
      aq[mi] = *(const bf16x8*)&Qt[wr2 + mi * 16 + r][kk + q8];
#pragma unroll
    for (int ni = 0; ni < 4; ni++)
      bp[ni] = *(const bf16x8*)&Ps[wc + ni * 16 + r][kk + q8];
#pragma unroll
    for (int mi = 0; mi < 3; mi++)
#pragma unroll
      for (int ni = 0; ni < 4; ni++)
        po[mi][ni] = __builtin_amdgcn_mfma_f32_16x16x32_bf16(aq[mi], bp[ni],
                                                             po[mi][ni], 0, 0, 0);
  }
#pragma unroll
  for (int mi = 0; mi < 3; mi++)
#pragma unroll
    for (int ni = 0; ni < 4; ni++) {
      int qcol = wc + ni * 16 + r;
      if (qcol < SS) {
        int d0 = wr2 + mi * 16 + quad * 4;
        __hip_bfloat16 hb[4];
#pragma unroll
        for (int rg = 0; rg < 4; rg++) hb[rg] = __float2bfloat16(po[mi][ni][rg]);
        *(short4v*)(out + (size_t)(b * SS + qcol) * DD + h * HD + d0) = *(short4v*)hb;
      }
    }
}

// ---------------- bf16 MFMA GEMM: C[M,N] = A[M,K] @ Bt[N,K]^T ----------------
// MODE 0: outf = C + bias; MODE 1: outb = gelu(C + bias) bf16; MODE 2: outf = C + bias + resid
template <int MODE>
__launch_bounds__(256)
__global__ void gemm_bt(const __hip_bfloat16* __restrict__ A,
                        const __hip_bfloat16* __restrict__ Bt,
                        const float* __restrict__ bias,
                        const float* __restrict__ resid,
                        float* __restrict__ outf,
                        __hip_bfloat16* __restrict__ outb,
                        int M, int N, int K) {
  constexpr int BM = 128, BN = 128, BK = 32;
  __shared__ __align__(16) __hip_bfloat16 As[BM * BK];
  __shared__ __align__(16) __hip_bfloat16 Bs[BN * BK];
  const int tid = threadIdx.x;
  const int wave = tid >> 6, lane = tid & 63;
  const int wr = (wave >> 1) * 64, wc = (wave & 1) * 64;
  const int m0 = blockIdx.y * BM, n0 = blockIdx.x * BN;
  const int r = lane & 15, q = lane >> 4;

  f32x4 acc[4][4] = {};

  for (int k0 = 0; k0 < K; k0 += BK) {
#pragma unroll
    for (int j = 0; j < 2; j++) {
      int li = tid + 256 * j;           // 0..511
      int row = li >> 2, cp = li & 3;   // 4 x 16B per 64B row
      async_copy16(As + li * 8, A + (size_t)(m0 + row) * K + k0 + cp * 8);
      async_copy16(Bs + li * 8, Bt + (size_t)(n0 + row) * K + k0 + cp * 8);
    }
    __syncthreads();
    bf16x8 af[4], bfr[4];
#pragma unroll
    for (int mi = 0; mi < 4; mi++)
      af[mi] = *(const bf16x8*)(As + (wr + mi * 16 + r) * BK + q * 8);
#pragma unroll
    for (int ni = 0; ni < 4; ni++)
      bfr[ni] = *(const bf16x8*)(Bs + (wc + ni * 16 + r) * BK + q * 8);
#pragma unroll
    for (int mi = 0; mi < 4; mi++)
#pragma unroll
      for (int ni = 0; ni < 4; ni++)
        acc[mi][ni] = __builtin_amdgcn_mfma_f32_16x16x32_bf16(af[mi], bfr[ni],
                                                              acc[mi][ni], 0, 0, 0);
    __syncthreads();
  }

#pragma unroll
  for (int mi = 0; mi < 4; mi++) {
#pragma unroll
    for (int ni = 0; ni < 4; ni++) {
      int col = n0 + wc + ni * 16 + r;
      float bv = bias[col];
#pragma unroll
      for (int rg = 0; rg < 4; rg++) {
        int row = m0 + wr + mi * 16 + q * 4 + rg;
        size_t oidx = (size_t)row * N + col;
        float v = acc[mi][ni][rg] + bv;
        if constexpr (MODE == 2) v += resid[oidx];
        if constexpr (MODE == 1) {
          v = 0.5f * v * (1.0f + erff(v * 0.70710678118654752f));
          outb[oidx] = __float2bfloat16(v);
        } else {
          outf[oidx] = v;
        }
      }
    }
  }
}

// ---------------- split-K classifier ----------------
#define CCHUNK 3072
#define NCHUNK 25   // 76800 / 3072
__global__ void classifier_part(const float* __restrict__ x,
                                const float* __restrict__ Wfc,
                                float* __restrict__ part) {
  int chunk = blockIdx.x, b = blockIdx.y, tid = threadIdx.x;
  const float* xb = x + (size_t)b * (SS * DD) + chunk * CCHUNK;
  const float* w = Wfc + 2 * (size_t)chunk * CCHUNK;
  float a0 = 0.f, a1 = 0.f;
  for (int i = tid; i < CCHUNK; i += 256) {
    float xv = xb[i];
    float2 wv = *(const float2*)(w + 2 * i);
    a0 += xv * wv.x;
    a1 += xv * wv.y;
  }
  __shared__ float sbuf[4];
  a0 = block_sum256(a0, sbuf);
  a1 = block_sum256(a1, sbuf);
  if (tid == 0) {
    part[(b * NCHUNK + chunk) * 2] = a0;
    part[(b * NCHUNK + chunk) * 2 + 1] = a1;
  }
}

__global__ void classifier_final(const float* __restrict__ part,
                                 const float* __restrict__ bfc,
                                 float* __restrict__ out) {
  int b = threadIdx.x;  // 64 threads
  float a0 = bfc[0], a1 = bfc[1];
#pragma unroll
  for (int c = 0; c < NCHUNK; c++) {
    a0 += part[(b * NCHUNK + c) * 2];
    a1 += part[(b * NCHUNK + c) * 2 + 1];
  }
  out[2 * b] = a0;
  out[2 * b + 1] = a1;
}

// ---------------- launcher ----------------
extern "C" void kernel_launch(void* const* d_in, const int* in_sizes, int n_in,
                              void* d_out, int out_size, void* d_ws, size_t ws_size,
                              hipStream_t stream) {
  const float* Tmpl = (const float*)d_in[0];
  const float* Pseq = (const float*)d_in[1];
  const float* Wc   = (const float*)d_in[2];
  const float* bc   = (const float*)d_in[3];
  const float* gp   = (const float*)d_in[4];
  const float* bp   = (const float*)d_in[5];
  const float* W1   = (const float*)d_in[6];
  const float* b1   = (const float*)d_in[7];
  const float* W2   = (const float*)d_in[8];
  const float* b2   = (const float*)d_in[9];
  const float* g1   = (const float*)d_in[10];
  const float* bn1  = (const float*)d_in[11];
  const float* g2   = (const float*)d_in[12];
  const float* bn2  = (const float*)d_in[13];
  const float* Wfc  = (const float*)d_in[14];
  const float* bfc  = (const float*)d_in[15];
  float* out = (float*)d_out;
  (void)in_sizes; (void)n_in; (void)out_size; (void)ws_size;

  char* ws = (char*)d_ws;
  size_t off = 0;
  auto alloc = [&](size_t n) { size_t o = off; off += (n + 255) & ~(size_t)255; return o; };

  __hip_bfloat16* Wct = (__hip_bfloat16*)(ws + alloc((size_t)768 * 768 * 2));
  __hip_bfloat16* W1t = (__hip_bfloat16*)(ws + alloc((size_t)768 * 3072 * 2));
  __hip_bfloat16* W2t = (__hip_bfloat16*)(ws + alloc((size_t)3072 * 768 * 2));
  size_t h1_off = alloc((size_t)ROWS * FF_ * 2);
  __hip_bfloat16* h1 = (__hip_bfloat16*)(ws + h1_off);
  float* param_enc = (float*)(ws + h1_off);            // alias: dead before h1 live
  size_t slb_off = alloc((size_t)ROWS * DD * 2);
  __hip_bfloat16* src_ln_bf = (__hip_bfloat16*)(ws + slb_off);
  __hip_bfloat16* pooled = (__hip_bfloat16*)(ws + slb_off);  // alias
  size_t ao_off = alloc((size_t)ROWS * DD * 4);
  __hip_bfloat16* attn_out_b = (__hip_bfloat16*)(ws + ao_off);
  float* pe_lin = (float*)(ws + ao_off);               // alias
  float* pbias = (float*)(ws + alloc((size_t)512 * SS * SS * 4));
  float* src = (float*)(ws + alloc((size_t)ROWS * DD * 4));
  float* src_ln = (float*)(ws + alloc((size_t)ROWS * DD * 4));
  float* z = (float*)(ws + alloc((size_t)ROWS * DD * 4));
  float* cpart = (float*)(ws + alloc((size_t)BB * NCHUNK * 2 * 4));

  // ---- layer-invariant precompute ----
  convert_transpose<<<dim3(768 / 32, 768 / 32), 256, 0, stream>>>(Wc, Wct, 768, 768);
  convert_transpose<<<dim3(3072 / 32, 768 / 32), 256, 0, stream>>>(W1, W1t, 768, 3072);
  convert_transpose<<<dim3(768 / 32, 3072 / 32), 256, 0, stream>>>(W2, W2t, 3072, 768);
  pool_mean<<<ROWS * DD / 256, 256, 0, stream>>>(Pseq, pooled);
  gemm_bt<0><<<dim3(DD / 128, ROWS / 128), 256, 0, stream>>>(
      pooled, Wct, bc, nullptr, pe_lin, nullptr, ROWS, DD, 768);
  ln_row<false, false, false><<<ROWS, 192, 0, stream>>>(
      pe_lin, nullptr, nullptr, gp, bp, param_enc, nullptr);
  param_bias_mfma<<<512, 256, 0, stream>>>(param_enc, pbias);
  add_pe<<<ROWS * DD / 256, 256, 0, stream>>>(Tmpl, src);

  // ---- 4 shared layers ----
  for (int l = 0; l < 4; ++l) {
    attn_fused_mfma<<<512, 256, 0, stream>>>(src, pbias, attn_out_b);
    ln_row<true, true, true><<<ROWS, 192, 0, stream>>>(
        nullptr, attn_out_b, src, g1, bn1, src_ln, src_ln_bf);
    gemm_bt<1><<<dim3(FF_ / 128, ROWS / 128), 256, 0, stream>>>(
        src_ln_bf, W1t, b1, nullptr, nullptr, h1, ROWS, FF_, DD);
    gemm_bt<2><<<dim3(DD / 128, ROWS / 128), 256, 0, stream>>>(
        h1, W2t, b2, src_ln, z, nullptr, ROWS, DD, FF_);
    ln_row<false, false, false><<<ROWS, 192, 0, stream>>>(
        z, nullptr, nullptr, g2, bn2, src, nullptr);
  }

  classifier_part<<<dim3(NCHUNK, BB), 256, 0, stream>>>(src, Wfc, cpart);
  classifier_final<<<1, 64, 0, stream>>>(cpart, bfc, out);
}